// Round 1
// 632.490 us; speedup vs baseline: 1.0109x; 1.0109x over previous
//
#include <hip/hip_runtime.h>

#define HDIM 192
#define EPS 1e-5f

typedef __attribute__((ext_vector_type(8))) _Float16 half8;
typedef __attribute__((ext_vector_type(4))) float floatx4;

__device__ __forceinline__ float h2f(ushort u) {
    union { ushort u; _Float16 h; } c; c.u = u; return (float)c.h;
}
__device__ __forceinline__ ushort f2h(float x) {
    _Float16 h = (_Float16)x;           // RTN
    union { _Float16 h; ushort u; } c; c.h = h; return c.u;
}
__device__ __forceinline__ uint4 pack8(const ushort* h) {
    uint4 p;
    p.x = h[0] | ((uint)h[1] << 16); p.y = h[2] | ((uint)h[3] << 16);
    p.z = h[4] | ((uint)h[5] << 16); p.w = h[6] | ((uint)h[7] << 16);
    return p;
}

// async global->LDS DMA, 16B per lane; LDS dest = wave-uniform base + lane*16
__device__ __forceinline__ void gload_lds16(const ushort* g, ushort* l) {
    __builtin_amdgcn_global_load_lds(
        (const __attribute__((address_space(1))) unsigned int*)g,
        (__attribute__((address_space(3))) unsigned int*)l, 16, 0, 0);
}

// Activation planes are CHUNK-PLANAR: element (row, c) lives at
// ((c/32)*Nrow + row)*32 + c%32.

// ---------------------------------------------------------------------------
// Merged weight prep: all 10 matrices in ONE launch.
// Each: W[K,192] fp32 -> frag-ordered single fp16 plane
// (per k-chunk: [ct(12)][lane(64)][j(8)] = 6144 ushorts).
// ---------------------------------------------------------------------------
struct PrepArgs {
    const float* src[6];
    ushort*      dst[6];
    int K[6];
    int off[7];       // thread offsets (per entry: nmat*(K/32)*12*64)
};

__global__ __launch_bounds__(256) void prep_all_k(PrepArgs a)
{
    int idx = blockIdx.x * 256 + threadIdx.x;
    if (idx >= a.off[6]) return;
    int i = 0;
    #pragma unroll
    for (int t = 1; t < 6; ++t) if (idx >= a.off[t]) i = t;
    int r = idx - a.off[i];
    int K = a.K[i];
    int perMat = (K >> 5) * 12 * 64;
    int mat = r / perMat;
    r -= mat * perMat;
    int lane = r & 63;
    int ct = (r >> 6) % 12;
    int kc = r / (12 * 64);
    int col = ct * 16 + (lane & 15);
    int kb  = kc * 32 + (lane >> 4) * 8;
    const float* Wm = a.src[i] + (size_t)mat * K * HDIM;
    ushort* base = a.dst[i] + (size_t)mat * K * HDIM;
    size_t o = (size_t)kc * 6144 + (size_t)(ct * 64 + lane) * 8;
    #pragma unroll
    for (int j = 0; j < 8; ++j)
        base[o + j] = f2h(Wm[(size_t)(kb + j) * HDIM + col]);
}

// ---------------------------------------------------------------------------
// fp32 row-major [R, C] -> fp16 chunk-planar. One thread per 8 channels.
// ---------------------------------------------------------------------------
__global__ __launch_bounds__(256) void conv_planar_k(
    const float* __restrict__ src, ushort* __restrict__ dst, int R, int C)
{
    int OC = C >> 3;
    int idx = blockIdx.x * 256 + threadIdx.x;
    if (idx >= R * OC) return;
    int r = idx / OC;
    int o = idx - r * OC;
    float4 v0 = ((const float4*)(src + (size_t)r * C + o * 8))[0];
    float4 v1 = ((const float4*)(src + (size_t)r * C + o * 8))[1];
    float v[8] = {v0.x, v0.y, v0.z, v0.w, v1.x, v1.y, v1.z, v1.w};
    ushort h[8];
    #pragma unroll
    for (int t = 0; t < 8; ++t) h[t] = f2h(v[t]);
    *(uint4*)(dst + ((size_t)(o >> 2) * R + r) * 32 + (o & 3) * 8) = pack8(h);
}

// ---------------------------------------------------------------------------
// MFMA GEMM: block 256 thr / 4 waves, tile 64 rows x 192 cols; wave tile
// 64x48.  A chunk (64x32 fp16 = 4KB) is staged ONCE per block into LDS via
// global_load_lds dwordx4 (1 op/thread/chunk, no VGPR round-trip) into a
// 2x4KB double buffer with a __syncthreads per chunk (m97 structure).  This
// removes the 4x redundant per-wave A loads of the old register path and
// deepens MLP via the DMA queue.  ds_read_b128 frag reads are bank-uniform
// (row stride 64B => 32B/bank/instr, no swizzle needed).  W stays as direct
// per-lane global loads (L2-resident), register double-buffered.
// C written fp16 CHUNK-PLANAR; BN stats from fp32 accs.
// ---------------------------------------------------------------------------
template<bool DUAL, bool RELU, bool DEG, bool STATS>
__global__ __launch_bounds__(256, 4) void gemm_mfma_k(
    const ushort* __restrict__ A1h, const ushort* __restrict__ W1f,
    const ushort* __restrict__ A2h, const ushort* __restrict__ W2f,
    const float* __restrict__ degf, const float* __restrict__ bias,
    ushort* __restrict__ C, float* __restrict__ stats, int N, int K)
{
    __shared__ float sstat[2][HDIM];
    __shared__ __align__(16) ushort sA[2][2048];   // 2 x 4KB A-chunk dbuf
    const int tid  = threadIdx.x;
    const int wave = tid >> 6;      // 0..3 = column group (48 cols each)
    const int lane = tid & 63;
    const int row0 = blockIdx.x * 64;
    const int m16 = lane & 15;
    const int g4  = lane >> 4;

    if (STATS && tid < HDIM) { sstat[0][tid] = 0.f; sstat[1][tid] = 0.f; }

    // stage source: thread t covers 16B at (row t/4, quarter t%3) of the
    // 64x32 chunk; clamp tail rows (same semantics as old per-lane clamp)
    int srow = row0 + (tid >> 2); if (srow >= N) srow = N - 1;
    const size_t soff = (size_t)srow * 32 + (size_t)(tid & 3) * 8;  // ushorts
    ushort* ldst0 = &sA[0][0] + wave * 512;   // wave-uniform, +lane*16B by HW
    ushort* ldst1 = &sA[1][0] + wave * 512;

    const int nkc = K >> 5;
    const int nch = DUAL ? 2 * nkc : nkc;   // always even here

    auto stageA = [&](int c, int buf) {
        bool ph = DUAL && (c >= nkc);
        int kc = ph ? c - nkc : c;
        const ushort* g = (ph ? A2h : A1h) + (size_t)kc * N * 32 + soff;
        gload_lds16(g, buf ? ldst1 : ldst0);
    };
    auto loadB = [&](int c, half8* b) {
        bool ph = DUAL && (c >= nkc);
        int kc = ph ? c - nkc : c;
        const ushort* Bp = (ph ? W2f : W1f) + (size_t)kc * 6144
                         + (size_t)(wave * 192 + lane) * 8;
        #pragma unroll
        for (int ct = 0; ct < 3; ++ct)
            b[ct] = *(const half8*)(Bp + ct * 512);
    };

    floatx4 acc[4][3];
    #pragma unroll
    for (int s = 0; s < 4; ++s)
        #pragma unroll
        for (int ct = 0; ct < 3; ++ct) acc[s][ct] = (floatx4){0.f, 0.f, 0.f, 0.f};

    auto compute = [&](int buf, half8* b) {
        const ushort* aB = (buf ? &sA[1][0] : &sA[0][0]) + m16 * 32 + g4 * 8;
        half8 a[4];
        #pragma unroll
        for (int s = 0; s < 4; ++s)
            a[s] = *(const half8*)(aB + s * 512);
        #pragma unroll
        for (int ct = 0; ct < 3; ++ct)
            #pragma unroll
            for (int s = 0; s < 4; ++s)
                acc[s][ct] = __builtin_amdgcn_mfma_f32_16x16x32_f16(a[s], b[ct], acc[s][ct], 0, 0, 0);
    };

    half8 b0[3], b1[3];
    stageA(0, 0); loadB(0, b0);
    __syncthreads();                        // stage(0) drained (vmcnt 0)
    for (int cc = 0; cc < nch; cc += 2) {
        stageA(cc + 1, 1);                  // nch even => cc+1 < nch
        loadB(cc + 1, b1);
        compute(0, b0);
        __syncthreads();                    // stage(cc+1)+B(cc+1) drained
        if (cc + 2 < nch) { stageA(cc + 2, 0); loadB(cc + 2, b0); }
        compute(1, b1);
        __syncthreads();                    // stage(cc+2)+B(cc+2) drained
    }

    // epilogue: C/D layout col=lane&15, row=(lane>>4)*4+reg  [m89]
    #pragma unroll
    for (int ct = 0; ct < 3; ++ct) {
        int col = wave * 48 + ct * 16 + m16;
        float bv = bias ? bias[col] : 0.f;
        ushort* Cc = C + (size_t)(col >> 5) * N * 32 + (col & 31);
        float lsum = 0.f, lsq = 0.f;
        #pragma unroll
        for (int s = 0; s < 4; ++s) {
            #pragma unroll
            for (int reg = 0; reg < 4; ++reg) {
                int rr = row0 + s * 16 + g4 * 4 + reg;
                if (rr < N) {
                    float v = acc[s][ct][reg] + (DEG ? degf[rr] * bv : bv);
                    if (STATS) { lsum += v; lsq += v * v; }
                    if (RELU) v = fmaxf(v, 0.f);
                    Cc[(size_t)rr * 32] = f2h(v);
                }
            }
        }
        if (STATS) {
            lsum += __shfl_xor(lsum, 16); lsum += __shfl_xor(lsum, 32);
            lsq  += __shfl_xor(lsq, 16);  lsq  += __shfl_xor(lsq, 32);
            if (g4 == 0) {
                atomicAdd(&sstat[0][col], lsum);
                atomicAdd(&sstat[1][col], lsq);
            }
        }
    }
    if (STATS) {
        __syncthreads();
        if (tid < HDIM) {
            atomicAdd(&stats[tid], sstat[0][tid]);
            atomicAdd(&stats[HDIM + tid], sstat[1][tid]);
        }
    }
}

// ---------------------------------------------------------------------------
// CSR construction from edge_dst
// ---------------------------------------------------------------------------
__global__ __launch_bounds__(256) void hist_k(
    const int* __restrict__ dst, int* __restrict__ deg, int E)
{
    int e = blockIdx.x * 256 + threadIdx.x;
    if (e < E) atomicAdd(&deg[dst[e]], 1);
}

__global__ __launch_bounds__(256) void block_sum_k(
    const int* __restrict__ deg, int* __restrict__ bsum, int N)
{
    __shared__ int s[256];
    int t = threadIdx.x;
    int n = blockIdx.x * 256 + t;
    s[t] = (n < N) ? deg[n] : 0;
    __syncthreads();
    for (int off = 128; off > 0; off >>= 1) {
        if (t < off) s[t] += s[t + off];
        __syncthreads();
    }
    if (t == 0) bsum[blockIdx.x] = s[0];
}

__global__ __launch_bounds__(512) void scan_bsum_k(int* __restrict__ bsum, int nb)
{
    __shared__ int s[512];
    int t = threadIdx.x;
    int v = (t < nb) ? bsum[t] : 0;
    s[t] = v;
    __syncthreads();
    for (int off = 1; off < 512; off <<= 1) {
        int u = (t >= off) ? s[t - off] : 0;
        __syncthreads();
        s[t] += u;
        __syncthreads();
    }
    if (t < nb) bsum[t] = s[t] - v;   // exclusive
}

__global__ __launch_bounds__(256) void row_ptr_k(
    const int* __restrict__ deg, const int* __restrict__ bsum,
    int* __restrict__ row_ptr, int* __restrict__ cursor,
    float* __restrict__ degf, int N, int E)
{
    __shared__ int s[256];
    int t = threadIdx.x;
    int n = blockIdx.x * 256 + t;
    int v = (n < N) ? deg[n] : 0;
    s[t] = v;
    __syncthreads();
    for (int off = 1; off < 256; off <<= 1) {
        int u = (t >= off) ? s[t - off] : 0;
        __syncthreads();
        s[t] += u;
        __syncthreads();
    }
    int ex = s[t] - v + bsum[blockIdx.x];
    if (n < N) {
        row_ptr[n] = ex;
        cursor[n]  = ex;
        degf[n]    = (float)v;
    }
    if (blockIdx.x == 0 && t == 0) row_ptr[N] = E;
}

__global__ __launch_bounds__(256) void fill_k(
    const int* __restrict__ src, const int* __restrict__ dst,
    int* __restrict__ cursor, int* __restrict__ col, int E)
{
    int e = blockIdx.x * 256 + threadIdx.x;
    if (e < E) {
        int p = atomicAdd(&cursor[dst[e]], 1);
        col[p] = src[e];
    }
}

// ---------------------------------------------------------------------------
// plain gather (layer 0, no BN): g[n] = sum_j x[col[j]]; planar fp16.
// ---------------------------------------------------------------------------
__global__ __launch_bounds__(256) void gather_h_k(
    const ushort* __restrict__ xh, const int* __restrict__ row_ptr,
    const int* __restrict__ col, ushort* __restrict__ gh, int N, int K)
{
    int OC = K >> 3;
    int idx = blockIdx.x * 256 + threadIdx.x;
    if (idx >= N * OC) return;
    int n = idx / OC;
    int o = idx - n * OC;
    size_t plane = (size_t)(o >> 2) * N * 32 + (o & 3) * 8;
    int j0 = row_ptr[n], j1 = row_ptr[n + 1];
    float acc[8] = {0.f,0.f,0.f,0.f,0.f,0.f,0.f,0.f};
    for (int j = j0; j < j1; ++j) {
        int s = col[j];
        uint4 hv = *(const uint4*)(xh + plane + (size_t)s * 32);
        uint hu[4] = {hv.x, hv.y, hv.z, hv.w};
        #pragma unroll
        for (int t = 0; t < 4; ++t) {
            acc[2*t]   += h2f((ushort)(hu[t] & 0xffffu));
            acc[2*t+1] += h2f((ushort)(hu[t] >> 16));
        }
    }
    ushort oh[8];
    #pragma unroll
    for (int t = 0; t < 8; ++t) oh[t] = f2h(acc[t]);
    *(uint4*)(gh + plane + (size_t)n * 32) = pack8(oh);
}

// ---------------------------------------------------------------------------
// fused BN-apply + gather (layers 1..3): reads raw conv h (planar), computes
// per-thread BN coeffs from raw sums, writes xh[n] = relu(bn(h[n])) and
// gh[n] = sum_j relu(bn(h[col j])).
// ---------------------------------------------------------------------------
__global__ __launch_bounds__(256) void gather_bn_k(
    const ushort* __restrict__ h, const float* __restrict__ stats,
    const float* __restrict__ gamma, const float* __restrict__ beta,
    float invN, const int* __restrict__ row_ptr, const int* __restrict__ col,
    ushort* __restrict__ xh, ushort* __restrict__ gh, int N)
{
    int idx = blockIdx.x * 256 + threadIdx.x;
    if (idx >= N * 24) return;
    int n = idx / 24;
    int o = idx - n * 24;
    int q = o * 8;
    float sc[8], sh[8];
    #pragma unroll
    for (int t = 0; t < 8; ++t) {
        float mu  = stats[q + t] * invN;
        float var = stats[HDIM + q + t] * invN - mu * mu;
        float s = gamma[q + t] * rsqrtf(var + EPS);
        sc[t] = s; sh[t] = beta[q + t] - mu * s;
    }
    size_t plane = (size_t)(o >> 2) * N * 32 + (o & 3) * 8;
    // own row -> xh
    {
        uint4 hv = *(const uint4*)(h + plane + (size_t)n * 32);
        uint hu[4] = {hv.x, hv.y, hv.z, hv.w};
        ushort oh[8];
        #pragma unroll
        for (int t = 0; t < 4; ++t) {
            float v0 = h2f((ushort)(hu[t] & 0xffffu));
            float v1 = h2f((ushort)(hu[t] >> 16));
            oh[2*t]   = f2h(fmaxf(v0 * sc[2*t]   + sh[2*t],   0.f));
            oh[2*t+1] = f2h(fmaxf(v1 * sc[2*t+1] + sh[2*t+1], 0.f));
        }
        *(uint4*)(xh + plane + (size_t)n * 32) = pack8(oh);
    }
    // neighbors -> gh
    int j0 = row_ptr[n], j1 = row_ptr[n + 1];
    float acc[8] = {0.f,0.f,0.f,0.f,0.f,0.f,0.f,0.f};
    for (int j = j0; j < j1; ++j) {
        int s = col[j];
        uint4 hv = *(const uint4*)(h + plane + (size_t)s * 32);
        uint hu[4] = {hv.x, hv.y, hv.z, hv.w};
        #pragma unroll
        for (int t = 0; t < 4; ++t) {
            float v0 = h2f((ushort)(hu[t] & 0xffffu));
            float v1 = h2f((ushort)(hu[t] >> 16));
            acc[2*t]   += fmaxf(v0 * sc[2*t]   + sh[2*t],   0.f);
            acc[2*t+1] += fmaxf(v1 * sc[2*t+1] + sh[2*t+1], 0.f);
        }
    }
    ushort oh[8];
    #pragma unroll
    for (int t = 0; t < 8; ++t) oh[t] = f2h(acc[t]);
    *(uint4*)(gh + plane + (size_t)n * 32) = pack8(oh);
}

// ---------------------------------------------------------------------------
// fused final-BN + mean-pool: block per graph, thread per channel.
// Graph row range via binary search in sorted batch[]. Output fp16 planar
// (Nrow=G), feeding the head GEMM directly.
// ---------------------------------------------------------------------------
__global__ __launch_bounds__(192) void pool_bn_k(
    const ushort* __restrict__ h, const float* __restrict__ stats,
    const float* __restrict__ gamma, const float* __restrict__ beta,
    float invN, const int* __restrict__ batch,
    ushort* __restrict__ gsh, int G, int N)
{
    __shared__ int bounds[2];
    int g = blockIdx.x;
    int c = threadIdx.x;
    if (c < 2) {
        int key = g + c;
        int lo = 0, hi = N;
        while (lo < hi) {
            int mid = (lo + hi) >> 1;
            if (batch[mid] < key) lo = mid + 1; else hi = mid;
        }
        bounds[c] = lo;
    }
    __syncthreads();
    int r0 = bounds[0], r1 = bounds[1];
    float mu  = stats[c] * invN;
    float var = stats[HDIM + c] * invN - mu * mu;
    float sc  = gamma[c] * rsqrtf(var + EPS);
    float sh  = beta[c] - mu * sc;
    const ushort* base = h + (size_t)(c >> 5) * N * 32 + (c & 31);
    float s = 0.f;
    for (int r = r0; r < r1; ++r)
        s += fmaxf(h2f(base[(size_t)r * 32]) * sc + sh, 0.f);
    float m = s / fmaxf((float)(r1 - r0), 1.f);
    gsh[((size_t)(c >> 5) * G + g) * 32 + (c & 31)] = f2h(m);
}

// ---------------------------------------------------------------------------
// out[g] = dot(g2[g,:], Wout) + bout ; g2 is fp16 chunk-planar
// ---------------------------------------------------------------------------
__global__ __launch_bounds__(64) void out_dot_k(
    const ushort* __restrict__ g2h, const float* __restrict__ Wout,
    const float* __restrict__ bout, float* __restrict__ out, int G)
{
    int gi = blockIdx.x;
    int t = threadIdx.x;
    float s = 0.f;
    #pragma unroll
    for (int j = 0; j < 3; ++j) {
        int c = t + j * 64;
        s += h2f(g2h[((size_t)(c >> 5) * G + gi) * 32 + (c & 31)]) * Wout[c];
    }
    #pragma unroll
    for (int off = 32; off > 0; off >>= 1) s += __shfl_down(s, off, 64);
    if (t == 0) out[gi] = s + bout[0];
}

// ---------------------------------------------------------------------------
extern "C" void kernel_launch(void* const* d_in, const int* in_sizes, int n_in,
                              void* d_out, int out_size, void* d_ws, size_t ws_size,
                              hipStream_t stream)
{
    const float* x      = (const float*)d_in[0];
    const int*   esrc   = (const int*)d_in[1];
    const int*   edst   = (const int*)d_in[2];
    const int*   batch  = (const int*)d_in[3];
    const float* Wrel0  = (const float*)d_in[4];
    const float* brel0  = (const float*)d_in[5];
    const float* Wroot0 = (const float*)d_in[6];
    const float* Wrel   = (const float*)d_in[7];
    const float* brel   = (const float*)d_in[8];
    const float* Wroot  = (const float*)d_in[9];
    const float* gamma  = (const float*)d_in[10];
    const float* beta   = (const float*)d_in[11];
    const float* Wh1    = (const float*)d_in[12];
    const float* bh1    = (const float*)d_in[13];
    const float* Wh2    = (const float*)d_in[14];
    const float* bh2    = (const float*)d_in[15];
    const float* Wout   = (const float*)d_in[16];
    const float* bout   = (const float*)d_in[17];
    float* out = (float*)d_out;

    const int N  = in_sizes[3];           // 100000
    const int E  = in_sizes[1];           // 400000
    const int K0 = in_sizes[0] / N;       // 32
    const int G  = out_size;              // 2000
    const int nBlocks = (N + 255) / 256;
    const float invN = 1.0f / (float)N;

    char* p = (char*)d_ws;
    auto carve = [&](size_t bytes) -> void* {
        void* r = (void*)p; p += (bytes + 255) & ~(size_t)255; return r;
    };
    ushort* bufa_h= (ushort*)carve((size_t)N * HDIM * 2);   // raw conv, planar fp16
    ushort* xh    = (ushort*)carve((size_t)N * HDIM * 2);
    ushort* gh    = (ushort*)carve((size_t)N * HDIM * 2);
    ushort* gsh   = (ushort*)carve((size_t)G * HDIM * 2);
    ushort* g1h   = (ushort*)carve((size_t)G * HDIM * 2);
    ushort* g2h   = (ushort*)carve((size_t)G * HDIM * 2);
    // deg + bnsums adjacent -> single memset
    int*    deg   = (int*)   carve((size_t)N * 4);
    float*  bnsums= (float*) carve(4 * 2 * HDIM * 4);
    size_t  zspan = (char*)(bnsums + 4 * 2 * HDIM) - (char*)deg;
    float*  degf  = (float*) carve((size_t)N * 4);
    int*    row_ptr=(int*)   carve((size_t)(N + 1) * 4);
    int*    cursor= (int*)   carve((size_t)N * 4);
    int*    col   = (int*)   carve((size_t)E * 4);
    int*    bsum  = (int*)   carve((size_t)nBlocks * 4);
    ushort* Wrel0f= (ushort*)carve((size_t)K0 * HDIM * 2);
    ushort* Wroot0f=(ushort*)carve((size_t)K0 * HDIM * 2);
    ushort* Wrelf = (ushort*)carve((size_t)3 * HDIM * HDIM * 2);
    ushort* Wrootf= (ushort*)carve((size_t)3 * HDIM * HDIM * 2);
    ushort* Wh1f  = (ushort*)carve((size_t)HDIM * HDIM * 2);
    ushort* Wh2f  = (ushort*)carve((size_t)HDIM * HDIM * 2);

    dim3 b256(256);
    const int eBlocks = (E + 255) / 256;
    const int gemmN = (N + 63) / 64;
    const int gemmG = (G + 63) / 64;

    // ---- merged weight prep (1 launch)
    {
        PrepArgs a;
        int t0 = (K0 >> 5) * 12 * 64;        // 768
        int t1 = (HDIM >> 5) * 12 * 64;      // 4608
        a.src[0] = Wrel0;  a.dst[0] = Wrel0f;  a.K[0] = K0;
        a.src[1] = Wroot0; a.dst[1] = Wroot0f; a.K[1] = K0;
        a.src[2] = Wrel;   a.dst[2] = Wrelf;   a.K[2] = HDIM;
        a.src[3] = Wroot;  a.dst[3] = Wrootf;  a.K[3] = HDIM;
        a.src[4] = Wh1;    a.dst[4] = Wh1f;    a.K[4] = HDIM;
        a.src[5] = Wh2;    a.dst[5] = Wh2f;    a.K[5] = HDIM;
        a.off[0] = 0;
        a.off[1] = a.off[0] + t0;
        a.off[2] = a.off[1] + t0;
        a.off[3] = a.off[2] + 3 * t1;
        a.off[4] = a.off[3] + 3 * t1;
        a.off[5] = a.off[4] + t1;
        a.off[6] = a.off[5] + t1;
        prep_all_k<<<(a.off[6] + 255) / 256, b256, 0, stream>>>(a);
    }
    // x -> planar fp16 (K0=32: planar == row-major)
    conv_planar_k<<<((N * (K0 >> 3)) + 255) / 256, b256, 0, stream>>>(x, xh, N, K0);

    // ---- CSR build
    hipMemsetAsync(deg, 0, zspan, stream);   // zeros deg + bnsums
    hist_k<<<eBlocks, b256, 0, stream>>>(edst, deg, E);
    block_sum_k<<<nBlocks, b256, 0, stream>>>(deg, bsum, N);
    scan_bsum_k<<<1, dim3(512), 0, stream>>>(bsum, nBlocks);
    row_ptr_k<<<nBlocks, b256, 0, stream>>>(deg, bsum, row_ptr, cursor, degf, N, E);
    fill_k<<<eBlocks, b256, 0, stream>>>(esrc, edst, cursor, col, E);

    // ---- layer 0 (input x, no BN on input)
    gather_h_k<<<((N * (K0 >> 3)) + 255) / 256, b256, 0, stream>>>(
        xh, row_ptr, col, gh, N, K0);
    gemm_mfma_k<true, false, true, true><<<gemmN, b256, 0, stream>>>(
        gh, Wrel0f, xh, Wroot0f, degf, brel0, bufa_h, bnsums, N, K0);

    // ---- layers 1..3: fused BN-apply + gather, then GEMM
    for (int l = 1; l < 4; ++l) {
        const ushort* Wrf = Wrelf  + (size_t)(l - 1) * HDIM * HDIM;
        const ushort* Wtf = Wrootf + (size_t)(l - 1) * HDIM * HDIM;
        const float*  br  = brel   + (size_t)(l - 1) * HDIM;
        gather_bn_k<<<(N * 24 + 255) / 256, b256, 0, stream>>>(
            bufa_h, bnsums + (l - 1) * 2 * HDIM,
            gamma + (l - 1) * HDIM, beta + (l - 1) * HDIM, invN,
            row_ptr, col, xh, gh, N);
        gemm_mfma_k<true, false, true, true><<<gemmN, b256, 0, stream>>>(
            gh, Wrf, xh, Wtf, degf, br, bufa_h, bnsums + l * 2 * HDIM, N, HDIM);
    }

    // ---- fused final BN + mean pool -> fp16 planar head input
    pool_bn_k<<<G, dim3(192), 0, stream>>>(
        bufa_h, bnsums + 3 * 2 * HDIM, gamma + 3 * HDIM, beta + 3 * HDIM,
        invN, batch, gsh, G, N);

    // ---- head MLP (MFMA path, planar fp16 end-to-end)
    gemm_mfma_k<false, true, false, false><<<gemmG, b256, 0, stream>>>(
        gsh, Wh1f, nullptr, nullptr, nullptr, bh1, g1h, nullptr, G, HDIM);
    gemm_mfma_k<false, false, false, false><<<gemmG, b256, 0, stream>>>(
        g1h, Wh2f, nullptr, nullptr, nullptr, bh2, g2h, nullptr, G, HDIM);
    out_dot_k<<<G, dim3(64), 0, stream>>>(g2h, Wout, bout, out, G);
}

// Round 2
// 626.339 us; speedup vs baseline: 1.0208x; 1.0098x over previous
//
#include <hip/hip_runtime.h>

#define HDIM 192
#define EPS 1e-5f

typedef __attribute__((ext_vector_type(8))) _Float16 half8;
typedef __attribute__((ext_vector_type(4))) float floatx4;

__device__ __forceinline__ float h2f(ushort u) {
    union { ushort u; _Float16 h; } c; c.u = u; return (float)c.h;
}
__device__ __forceinline__ ushort f2h(float x) {
    _Float16 h = (_Float16)x;           // RTN
    union { _Float16 h; ushort u; } c; c.h = h; return c.u;
}
__device__ __forceinline__ uint4 pack8(const ushort* h) {
    uint4 p;
    p.x = h[0] | ((uint)h[1] << 16); p.y = h[2] | ((uint)h[3] << 16);
    p.z = h[4] | ((uint)h[5] << 16); p.w = h[6] | ((uint)h[7] << 16);
    return p;
}

// async global->LDS DMA, 16B per lane; LDS dest = wave-uniform base + lane*16
__device__ __forceinline__ void gload_lds16(const ushort* g, ushort* l) {
    __builtin_amdgcn_global_load_lds(
        (const __attribute__((address_space(1))) unsigned int*)g,
        (__attribute__((address_space(3))) unsigned int*)l, 16, 0, 0);
}

// counted waits: each K-chunk "window" is exactly 4 VMEM ops per thread
// (1 A-stage DMA + 3 B b128 loads).  vmcnt is in-order [m135], so waiting
// vmcnt(4) completes everything except the newest window.  "memory" clobber
// pins all loads/DMAs inside their window.
#define WAITV4() asm volatile("s_waitcnt vmcnt(4)" ::: "memory")
#define WAITV0() asm volatile("s_waitcnt vmcnt(0)" ::: "memory")

// Activation planes are CHUNK-PLANAR: element (row, c) lives at
// ((c/32)*Nrow + row)*32 + c%32.

// ---------------------------------------------------------------------------
// Merged weight prep: all 10 matrices in ONE launch.
// Each: W[K,192] fp32 -> frag-ordered single fp16 plane
// (per k-chunk: [ct(12)][lane(64)][j(8)] = 6144 ushorts).
// ---------------------------------------------------------------------------
struct PrepArgs {
    const float* src[6];
    ushort*      dst[6];
    int K[6];
    int off[7];       // thread offsets (per entry: nmat*(K/32)*12*64)
};

__global__ __launch_bounds__(256) void prep_all_k(PrepArgs a)
{
    int idx = blockIdx.x * 256 + threadIdx.x;
    if (idx >= a.off[6]) return;
    int i = 0;
    #pragma unroll
    for (int t = 1; t < 6; ++t) if (idx >= a.off[t]) i = t;
    int r = idx - a.off[i];
    int K = a.K[i];
    int perMat = (K >> 5) * 12 * 64;
    int mat = r / perMat;
    r -= mat * perMat;
    int lane = r & 63;
    int ct = (r >> 6) % 12;
    int kc = r / (12 * 64);
    int col = ct * 16 + (lane & 15);
    int kb  = kc * 32 + (lane >> 4) * 8;
    const float* Wm = a.src[i] + (size_t)mat * K * HDIM;
    ushort* base = a.dst[i] + (size_t)mat * K * HDIM;
    size_t o = (size_t)kc * 6144 + (size_t)(ct * 64 + lane) * 8;
    #pragma unroll
    for (int j = 0; j < 8; ++j)
        base[o + j] = f2h(Wm[(size_t)(kb + j) * HDIM + col]);
}

// ---------------------------------------------------------------------------
// fp32 row-major [R, C] -> fp16 chunk-planar. One thread per 8 channels.
// ---------------------------------------------------------------------------
__global__ __launch_bounds__(256) void conv_planar_k(
    const float* __restrict__ src, ushort* __restrict__ dst, int R, int C)
{
    int OC = C >> 3;
    int idx = blockIdx.x * 256 + threadIdx.x;
    if (idx >= R * OC) return;
    int r = idx / OC;
    int o = idx - r * OC;
    float4 v0 = ((const float4*)(src + (size_t)r * C + o * 8))[0];
    float4 v1 = ((const float4*)(src + (size_t)r * C + o * 8))[1];
    float v[8] = {v0.x, v0.y, v0.z, v0.w, v1.x, v1.y, v1.z, v1.w};
    ushort h[8];
    #pragma unroll
    for (int t = 0; t < 8; ++t) h[t] = f2h(v[t]);
    *(uint4*)(dst + ((size_t)(o >> 2) * R + r) * 32 + (o & 3) * 8) = pack8(h);
}

// ---------------------------------------------------------------------------
// MFMA GEMM: block 256 thr / 4 waves, tile 64 rows x 192 cols; wave tile
// 64x48.  T3+T4 counted-vmcnt pipeline (never drain vmcnt(0) in the loop):
// A chunk (64x32 fp16 = 4KB) staged into a 2x4KB LDS double buffer via
// global_load_lds dwordx4; B (3x b128/lane) register double-buffered.
// Per chunk the wave issues exactly 4 VMEM ops, so at the consume point the
// wave waits vmcnt(4) -- chunk c complete, chunk c+1 stays IN FLIGHT across
// the raw s_barrier.  Second raw barrier fences the LDS buffer overwrite.
// C written fp16 CHUNK-PLANAR; BN stats from fp32 accs.
// ---------------------------------------------------------------------------
template<bool DUAL, bool RELU, bool DEG, bool STATS>
__global__ __launch_bounds__(256, 4) void gemm_mfma_k(
    const ushort* __restrict__ A1h, const ushort* __restrict__ W1f,
    const ushort* __restrict__ A2h, const ushort* __restrict__ W2f,
    const float* __restrict__ degf, const float* __restrict__ bias,
    ushort* __restrict__ C, float* __restrict__ stats, int N, int K)
{
    __shared__ float sstat[2][HDIM];
    __shared__ __align__(16) ushort sA[2][2048];   // 2 x 4KB A-chunk dbuf
    const int tid  = threadIdx.x;
    const int wave = tid >> 6;      // 0..3 = column group (48 cols each)
    const int lane = tid & 63;
    const int row0 = blockIdx.x * 64;
    const int m16 = lane & 15;
    const int g4  = lane >> 4;

    if (STATS && tid < HDIM) { sstat[0][tid] = 0.f; sstat[1][tid] = 0.f; }

    // stage source: thread t covers 16B at (row t/4, quarter t%3) of the
    // 64x32 chunk; clamp tail rows (same semantics as old per-lane clamp)
    int srow = row0 + (tid >> 2); if (srow >= N) srow = N - 1;
    const size_t soff = (size_t)srow * 32 + (size_t)(tid & 3) * 8;  // ushorts
    ushort* ldst0 = &sA[0][0] + wave * 512;   // wave-uniform, +lane*16B by HW
    ushort* ldst1 = &sA[1][0] + wave * 512;

    const int nkc = K >> 5;
    const int nch = DUAL ? 2 * nkc : nkc;   // always even here (2, 6 or 12)

    auto stageA = [&](int c, int buf) {
        bool ph = DUAL && (c >= nkc);
        int kc = ph ? c - nkc : c;
        const ushort* g = (ph ? A2h : A1h) + (size_t)kc * N * 32 + soff;
        gload_lds16(g, buf ? ldst1 : ldst0);
    };
    auto loadB = [&](int c, half8* b) {
        bool ph = DUAL && (c >= nkc);
        int kc = ph ? c - nkc : c;
        const ushort* Bp = (ph ? W2f : W1f) + (size_t)kc * 6144
                         + (size_t)(wave * 192 + lane) * 8;
        #pragma unroll
        for (int ct = 0; ct < 3; ++ct)
            b[ct] = *(const half8*)(Bp + ct * 512);
    };

    floatx4 acc[4][3];
    #pragma unroll
    for (int s = 0; s < 4; ++s)
        #pragma unroll
        for (int ct = 0; ct < 3; ++ct) acc[s][ct] = (floatx4){0.f, 0.f, 0.f, 0.f};

    auto compute = [&](int buf, half8* b) {
        const ushort* aB = (buf ? &sA[1][0] : &sA[0][0]) + m16 * 32 + g4 * 8;
        half8 a[4];
        #pragma unroll
        for (int s = 0; s < 4; ++s)
            a[s] = *(const half8*)(aB + s * 512);
        #pragma unroll
        for (int ct = 0; ct < 3; ++ct)
            #pragma unroll
            for (int s = 0; s < 4; ++s)
                acc[s][ct] = __builtin_amdgcn_mfma_f32_16x16x32_f16(a[s], b[ct], acc[s][ct], 0, 0, 0);
    };

    half8 b0[3], b1[3];
    stageA(0, 0); loadB(0, b0);     // window 0: 4 VMEM ops
    stageA(1, 1); loadB(1, b1);     // window 1: 4 VMEM ops
    for (int cc = 0; cc < nch; cc += 2) {
        // ---- chunk cc (buf 0, b0); cc+1 always < nch (nch even)
        WAITV4();                               // window cc done; cc+1 in flight
        __builtin_amdgcn_s_barrier();           // A(cc) visible to all waves
        __builtin_amdgcn_sched_barrier(0);
        compute(0, b0);
        __builtin_amdgcn_s_barrier();           // all waves done reading buf0
        __builtin_amdgcn_sched_barrier(0);
        if (cc + 2 < nch) { stageA(cc + 2, 0); loadB(cc + 2, b0); }
        // ---- chunk cc+1 (buf 1, b1)
        if (cc + 2 < nch) WAITV4(); else WAITV0();
        __builtin_amdgcn_s_barrier();
        __builtin_amdgcn_sched_barrier(0);
        compute(1, b1);
        __builtin_amdgcn_s_barrier();
        __builtin_amdgcn_sched_barrier(0);
        if (cc + 3 < nch) { stageA(cc + 3, 1); loadB(cc + 3, b1); }
    }

    // epilogue: C/D layout col=lane&15, row=(lane>>4)*4+reg  [m89]
    #pragma unroll
    for (int ct = 0; ct < 3; ++ct) {
        int col = wave * 48 + ct * 16 + m16;
        float bv = bias ? bias[col] : 0.f;
        ushort* Cc = C + (size_t)(col >> 5) * N * 32 + (col & 31);
        float lsum = 0.f, lsq = 0.f;
        #pragma unroll
        for (int s = 0; s < 4; ++s) {
            #pragma unroll
            for (int reg = 0; reg < 4; ++reg) {
                int rr = row0 + s * 16 + g4 * 4 + reg;
                if (rr < N) {
                    float v = acc[s][ct][reg] + (DEG ? degf[rr] * bv : bv);
                    if (STATS) { lsum += v; lsq += v * v; }
                    if (RELU) v = fmaxf(v, 0.f);
                    Cc[(size_t)rr * 32] = f2h(v);
                }
            }
        }
        if (STATS) {
            lsum += __shfl_xor(lsum, 16); lsum += __shfl_xor(lsum, 32);
            lsq  += __shfl_xor(lsq, 16);  lsq  += __shfl_xor(lsq, 32);
            if (g4 == 0) {
                atomicAdd(&sstat[0][col], lsum);
                atomicAdd(&sstat[1][col], lsq);
            }
        }
    }
    if (STATS) {
        __syncthreads();
        if (tid < HDIM) {
            atomicAdd(&stats[tid], sstat[0][tid]);
            atomicAdd(&stats[HDIM + tid], sstat[1][tid]);
        }
    }
}

// ---------------------------------------------------------------------------
// CSR construction from edge_dst
// ---------------------------------------------------------------------------
__global__ __launch_bounds__(256) void hist_k(
    const int* __restrict__ dst, int* __restrict__ deg, int E)
{
    int e = blockIdx.x * 256 + threadIdx.x;
    if (e < E) atomicAdd(&deg[dst[e]], 1);
}

__global__ __launch_bounds__(256) void block_sum_k(
    const int* __restrict__ deg, int* __restrict__ bsum, int N)
{
    __shared__ int s[256];
    int t = threadIdx.x;
    int n = blockIdx.x * 256 + t;
    s[t] = (n < N) ? deg[n] : 0;
    __syncthreads();
    for (int off = 128; off > 0; off >>= 1) {
        if (t < off) s[t] += s[t + off];
        __syncthreads();
    }
    if (t == 0) bsum[blockIdx.x] = s[0];
}

__global__ __launch_bounds__(512) void scan_bsum_k(int* __restrict__ bsum, int nb)
{
    __shared__ int s[512];
    int t = threadIdx.x;
    int v = (t < nb) ? bsum[t] : 0;
    s[t] = v;
    __syncthreads();
    for (int off = 1; off < 512; off <<= 1) {
        int u = (t >= off) ? s[t - off] : 0;
        __syncthreads();
        s[t] += u;
        __syncthreads();
    }
    if (t < nb) bsum[t] = s[t] - v;   // exclusive
}

__global__ __launch_bounds__(256) void row_ptr_k(
    const int* __restrict__ deg, const int* __restrict__ bsum,
    int* __restrict__ row_ptr, int* __restrict__ cursor,
    float* __restrict__ degf, int N, int E)
{
    __shared__ int s[256];
    int t = threadIdx.x;
    int n = blockIdx.x * 256 + t;
    int v = (n < N) ? deg[n] : 0;
    s[t] = v;
    __syncthreads();
    for (int off = 1; off < 256; off <<= 1) {
        int u = (t >= off) ? s[t - off] : 0;
        __syncthreads();
        s[t] += u;
        __syncthreads();
    }
    int ex = s[t] - v + bsum[blockIdx.x];
    if (n < N) {
        row_ptr[n] = ex;
        cursor[n]  = ex;
        degf[n]    = (float)v;
    }
    if (blockIdx.x == 0 && t == 0) row_ptr[N] = E;
}

__global__ __launch_bounds__(256) void fill_k(
    const int* __restrict__ src, const int* __restrict__ dst,
    int* __restrict__ cursor, int* __restrict__ col, int E)
{
    int e = blockIdx.x * 256 + threadIdx.x;
    if (e < E) {
        int p = atomicAdd(&cursor[dst[e]], 1);
        col[p] = src[e];
    }
}

// ---------------------------------------------------------------------------
// plain gather (layer 0, no BN): g[n] = sum_j x[col[j]]; planar fp16.
// ---------------------------------------------------------------------------
__global__ __launch_bounds__(256) void gather_h_k(
    const ushort* __restrict__ xh, const int* __restrict__ row_ptr,
    const int* __restrict__ col, ushort* __restrict__ gh, int N, int K)
{
    int OC = K >> 3;
    int idx = blockIdx.x * 256 + threadIdx.x;
    if (idx >= N * OC) return;
    int n = idx / OC;
    int o = idx - n * OC;
    size_t plane = (size_t)(o >> 2) * N * 32 + (o & 3) * 8;
    int j0 = row_ptr[n], j1 = row_ptr[n + 1];
    float acc[8] = {0.f,0.f,0.f,0.f,0.f,0.f,0.f,0.f};
    for (int j = j0; j < j1; ++j) {
        int s = col[j];
        uint4 hv = *(const uint4*)(xh + plane + (size_t)s * 32);
        uint hu[4] = {hv.x, hv.y, hv.z, hv.w};
        #pragma unroll
        for (int t = 0; t < 4; ++t) {
            acc[2*t]   += h2f((ushort)(hu[t] & 0xffffu));
            acc[2*t+1] += h2f((ushort)(hu[t] >> 16));
        }
    }
    ushort oh[8];
    #pragma unroll
    for (int t = 0; t < 8; ++t) oh[t] = f2h(acc[t]);
    *(uint4*)(gh + plane + (size_t)n * 32) = pack8(oh);
}

// ---------------------------------------------------------------------------
// fused BN-apply + gather (layers 1..3): reads raw conv h (planar), computes
// per-thread BN coeffs from raw sums, writes xh[n] = relu(bn(h[n])) and
// gh[n] = sum_j relu(bn(h[col j])).
// ---------------------------------------------------------------------------
__global__ __launch_bounds__(256) void gather_bn_k(
    const ushort* __restrict__ h, const float* __restrict__ stats,
    const float* __restrict__ gamma, const float* __restrict__ beta,
    float invN, const int* __restrict__ row_ptr, const int* __restrict__ col,
    ushort* __restrict__ xh, ushort* __restrict__ gh, int N)
{
    int idx = blockIdx.x * 256 + threadIdx.x;
    if (idx >= N * 24) return;
    int n = idx / 24;
    int o = idx - n * 24;
    int q = o * 8;
    float sc[8], sh[8];
    #pragma unroll
    for (int t = 0; t < 8; ++t) {
        float mu  = stats[q + t] * invN;
        float var = stats[HDIM + q + t] * invN - mu * mu;
        float s = gamma[q + t] * rsqrtf(var + EPS);
        sc[t] = s; sh[t] = beta[q + t] - mu * s;
    }
    size_t plane = (size_t)(o >> 2) * N * 32 + (o & 3) * 8;
    // own row -> xh
    {
        uint4 hv = *(const uint4*)(h + plane + (size_t)n * 32);
        uint hu[4] = {hv.x, hv.y, hv.z, hv.w};
        ushort oh[8];
        #pragma unroll
        for (int t = 0; t < 4; ++t) {
            float v0 = h2f((ushort)(hu[t] & 0xffffu));
            float v1 = h2f((ushort)(hu[t] >> 16));
            oh[2*t]   = f2h(fmaxf(v0 * sc[2*t]   + sh[2*t],   0.f));
            oh[2*t+1] = f2h(fmaxf(v1 * sc[2*t+1] + sh[2*t+1], 0.f));
        }
        *(uint4*)(xh + plane + (size_t)n * 32) = pack8(oh);
    }
    // neighbors -> gh
    int j0 = row_ptr[n], j1 = row_ptr[n + 1];
    float acc[8] = {0.f,0.f,0.f,0.f,0.f,0.f,0.f,0.f};
    for (int j = j0; j < j1; ++j) {
        int s = col[j];
        uint4 hv = *(const uint4*)(h + plane + (size_t)s * 32);
        uint hu[4] = {hv.x, hv.y, hv.z, hv.w};
        #pragma unroll
        for (int t = 0; t < 4; ++t) {
            float v0 = h2f((ushort)(hu[t] & 0xffffu));
            float v1 = h2f((ushort)(hu[t] >> 16));
            acc[2*t]   += fmaxf(v0 * sc[2*t]   + sh[2*t],   0.f);
            acc[2*t+1] += fmaxf(v1 * sc[2*t+1] + sh[2*t+1], 0.f);
        }
    }
    ushort oh[8];
    #pragma unroll
    for (int t = 0; t < 8; ++t) oh[t] = f2h(acc[t]);
    *(uint4*)(gh + plane + (size_t)n * 32) = pack8(oh);
}

// ---------------------------------------------------------------------------
// fused final-BN + mean-pool: block per graph, thread per channel.
// Graph row range via binary search in sorted batch[]. Output fp16 planar
// (Nrow=G), feeding the head GEMM directly.
// ---------------------------------------------------------------------------
__global__ __launch_bounds__(192) void pool_bn_k(
    const ushort* __restrict__ h, const float* __restrict__ stats,
    const float* __restrict__ gamma, const float* __restrict__ beta,
    float invN, const int* __restrict__ batch,
    ushort* __restrict__ gsh, int G, int N)
{
    __shared__ int bounds[2];
    int g = blockIdx.x;
    int c = threadIdx.x;
    if (c < 2) {
        int key = g + c;
        int lo = 0, hi = N;
        while (lo < hi) {
            int mid = (lo + hi) >> 1;
            if (batch[mid] < key) lo = mid + 1; else hi = mid;
        }
        bounds[c] = lo;
    }
    __syncthreads();
    int r0 = bounds[0], r1 = bounds[1];
    float mu  = stats[c] * invN;
    float var = stats[HDIM + c] * invN - mu * mu;
    float sc  = gamma[c] * rsqrtf(var + EPS);
    float sh  = beta[c] - mu * sc;
    const ushort* base = h + (size_t)(c >> 5) * N * 32 + (c & 31);
    float s = 0.f;
    for (int r = r0; r < r1; ++r)
        s += fmaxf(h2f(base[(size_t)r * 32]) * sc + sh, 0.f);
    float m = s / fmaxf((float)(r1 - r0), 1.f);
    gsh[((size_t)(c >> 5) * G + g) * 32 + (c & 31)] = f2h(m);
}

// ---------------------------------------------------------------------------
// out[g] = dot(g2[g,:], Wout) + bout ; g2 is fp16 chunk-planar
// ---------------------------------------------------------------------------
__global__ __launch_bounds__(64) void out_dot_k(
    const ushort* __restrict__ g2h, const float* __restrict__ Wout,
    const float* __restrict__ bout, float* __restrict__ out, int G)
{
    int gi = blockIdx.x;
    int t = threadIdx.x;
    float s = 0.f;
    #pragma unroll
    for (int j = 0; j < 3; ++j) {
        int c = t + j * 64;
        s += h2f(g2h[((size_t)(c >> 5) * G + gi) * 32 + (c & 31)]) * Wout[c];
    }
    #pragma unroll
    for (int off = 32; off > 0; off >>= 1) s += __shfl_down(s, off, 64);
    if (t == 0) out[gi] = s + bout[0];
}

// ---------------------------------------------------------------------------
extern "C" void kernel_launch(void* const* d_in, const int* in_sizes, int n_in,
                              void* d_out, int out_size, void* d_ws, size_t ws_size,
                              hipStream_t stream)
{
    const float* x      = (const float*)d_in[0];
    const int*   esrc   = (const int*)d_in[1];
    const int*   edst   = (const int*)d_in[2];
    const int*   batch  = (const int*)d_in[3];
    const float* Wrel0  = (const float*)d_in[4];
    const float* brel0  = (const float*)d_in[5];
    const float* Wroot0 = (const float*)d_in[6];
    const float* Wrel   = (const float*)d_in[7];
    const float* brel   = (const float*)d_in[8];
    const float* Wroot  = (const float*)d_in[9];
    const float* gamma  = (const float*)d_in[10];
    const float* beta   = (const float*)d_in[11];
    const float* Wh1    = (const float*)d_in[12];
    const float* bh1    = (const float*)d_in[13];
    const float* Wh2    = (const float*)d_in[14];
    const float* bh2    = (const float*)d_in[15];
    const float* Wout   = (const float*)d_in[16];
    const float* bout   = (const float*)d_in[17];
    float* out = (float*)d_out;

    const int N  = in_sizes[3];           // 100000
    const int E  = in_sizes[1];           // 400000
    const int K0 = in_sizes[0] / N;       // 32
    const int G  = out_size;              // 2000
    const int nBlocks = (N + 255) / 256;
    const float invN = 1.0f / (float)N;

    char* p = (char*)d_ws;
    auto carve = [&](size_t bytes) -> void* {
        void* r = (void*)p; p += (bytes + 255) & ~(size_t)255; return r;
    };
    ushort* bufa_h= (ushort*)carve((size_t)N * HDIM * 2);   // raw conv, planar fp16
    ushort* xh    = (ushort*)carve((size_t)N * HDIM * 2);
    ushort* gh    = (ushort*)carve((size_t)N * HDIM * 2);
    ushort* gsh   = (ushort*)carve((size_t)G * HDIM * 2);
    ushort* g1h   = (ushort*)carve((size_t)G * HDIM * 2);
    ushort* g2h   = (ushort*)carve((size_t)G * HDIM * 2);
    // deg + bnsums adjacent -> single memset
    int*    deg   = (int*)   carve((size_t)N * 4);
    float*  bnsums= (float*) carve(4 * 2 * HDIM * 4);
    size_t  zspan = (char*)(bnsums + 4 * 2 * HDIM) - (char*)deg;
    float*  degf  = (float*) carve((size_t)N * 4);
    int*    row_ptr=(int*)   carve((size_t)(N + 1) * 4);
    int*    cursor= (int*)   carve((size_t)N * 4);
    int*    col   = (int*)   carve((size_t)E * 4);
    int*    bsum  = (int*)   carve((size_t)nBlocks * 4);
    ushort* Wrel0f= (ushort*)carve((size_t)K0 * HDIM * 2);
    ushort* Wroot0f=(ushort*)carve((size_t)K0 * HDIM * 2);
    ushort* Wrelf = (ushort*)carve((size_t)3 * HDIM * HDIM * 2);
    ushort* Wrootf= (ushort*)carve((size_t)3 * HDIM * HDIM * 2);
    ushort* Wh1f  = (ushort*)carve((size_t)HDIM * HDIM * 2);
    ushort* Wh2f  = (ushort*)carve((size_t)HDIM * HDIM * 2);

    dim3 b256(256);
    const int eBlocks = (E + 255) / 256;
    const int gemmN = (N + 63) / 64;
    const int gemmG = (G + 63) / 64;

    // ---- merged weight prep (1 launch)
    {
        PrepArgs a;
        int t0 = (K0 >> 5) * 12 * 64;        // 768
        int t1 = (HDIM >> 5) * 12 * 64;      // 4608
        a.src[0] = Wrel0;  a.dst[0] = Wrel0f;  a.K[0] = K0;
        a.src[1] = Wroot0; a.dst[1] = Wroot0f; a.K[1] = K0;
        a.src[2] = Wrel;   a.dst[2] = Wrelf;   a.K[2] = HDIM;
        a.src[3] = Wroot;  a.dst[3] = Wrootf;  a.K[3] = HDIM;
        a.src[4] = Wh1;    a.dst[4] = Wh1f;    a.K[4] = HDIM;
        a.src[5] = Wh2;    a.dst[5] = Wh2f;    a.K[5] = HDIM;
        a.off[0] = 0;
        a.off[1] = a.off[0] + t0;
        a.off[2] = a.off[1] + t0;
        a.off[3] = a.off[2] + 3 * t1;
        a.off[4] = a.off[3] + 3 * t1;
        a.off[5] = a.off[4] + t1;
        a.off[6] = a.off[5] + t1;
        prep_all_k<<<(a.off[6] + 255) / 256, b256, 0, stream>>>(a);
    }
    // x -> planar fp16 (K0=32: planar == row-major)
    conv_planar_k<<<((N * (K0 >> 3)) + 255) / 256, b256, 0, stream>>>(x, xh, N, K0);

    // ---- CSR build
    hipMemsetAsync(deg, 0, zspan, stream);   // zeros deg + bnsums
    hist_k<<<eBlocks, b256, 0, stream>>>(edst, deg, E);
    block_sum_k<<<nBlocks, b256, 0, stream>>>(deg, bsum, N);
    scan_bsum_k<<<1, dim3(512), 0, stream>>>(bsum, nBlocks);
    row_ptr_k<<<nBlocks, b256, 0, stream>>>(deg, bsum, row_ptr, cursor, degf, N, E);
    fill_k<<<eBlocks, b256, 0, stream>>>(esrc, edst, cursor, col, E);

    // ---- layer 0 (input x, no BN on input)
    gather_h_k<<<((N * (K0 >> 3)) + 255) / 256, b256, 0, stream>>>(
        xh, row_ptr, col, gh, N, K0);
    gemm_mfma_k<true, false, true, true><<<gemmN, b256, 0, stream>>>(
        gh, Wrel0f, xh, Wroot0f, degf, brel0, bufa_h, bnsums, N, K0);

    // ---- layers 1..3: fused BN-apply + gather, then GEMM
    for (int l = 1; l < 4; ++l) {
        const ushort* Wrf = Wrelf  + (size_t)(l - 1) * HDIM * HDIM;
        const ushort* Wtf = Wrootf + (size_t)(l - 1) * HDIM * HDIM;
        const float*  br  = brel   + (size_t)(l - 1) * HDIM;
        gather_bn_k<<<(N * 24 + 255) / 256, b256, 0, stream>>>(
            bufa_h, bnsums + (l - 1) * 2 * HDIM,
            gamma + (l - 1) * HDIM, beta + (l - 1) * HDIM, invN,
            row_ptr, col, xh, gh, N);
        gemm_mfma_k<true, false, true, true><<<gemmN, b256, 0, stream>>>(
            gh, Wrf, xh, Wtf, degf, br, bufa_h, bnsums + l * 2 * HDIM, N, HDIM);
    }

    // ---- fused final BN + mean pool -> fp16 planar head input
    pool_bn_k<<<G, dim3(192), 0, stream>>>(
        bufa_h, bnsums + 3 * 2 * HDIM, gamma + 3 * HDIM, beta + 3 * HDIM,
        invN, batch, gsh, G, N);

    // ---- head MLP (MFMA path, planar fp16 end-to-end)
    gemm_mfma_k<false, true, false, false><<<gemmG, b256, 0, stream>>>(
        gsh, Wh1f, nullptr, nullptr, nullptr, bh1, g1h, nullptr, G, HDIM);
    gemm_mfma_k<false, false, false, false><<<gemmG, b256, 0, stream>>>(
        g1h, Wh2f, nullptr, nullptr, nullptr, bh2, g2h, nullptr, G, HDIM);
    out_dot_k<<<G, dim3(64), 0, stream>>>(g2h, Wout, bout, out, G);
}

// Round 3
// 564.258 us; speedup vs baseline: 1.1331x; 1.1100x over previous
//
#include <hip/hip_runtime.h>

#define HDIM 192
#define EPS 1e-5f

typedef __attribute__((ext_vector_type(8))) _Float16 half8;
typedef __attribute__((ext_vector_type(4))) float floatx4;

__device__ __forceinline__ float h2f(ushort u) {
    union { ushort u; _Float16 h; } c; c.u = u; return (float)c.h;
}
__device__ __forceinline__ ushort f2h(float x) {
    _Float16 h = (_Float16)x;           // RTN
    union { _Float16 h; ushort u; } c; c.h = h; return c.u;
}
__device__ __forceinline__ uint4 pack8(const ushort* h) {
    uint4 p;
    p.x = h[0] | ((uint)h[1] << 16); p.y = h[2] | ((uint)h[3] << 16);
    p.z = h[4] | ((uint)h[5] << 16); p.w = h[6] | ((uint)h[7] << 16);
    return p;
}

// async global->LDS DMA, 16B per lane; LDS dest = wave-uniform base + lane*16
__device__ __forceinline__ void gload_lds16(const ushort* g, ushort* l) {
    __builtin_amdgcn_global_load_lds(
        (const __attribute__((address_space(1))) unsigned int*)g,
        (__attribute__((address_space(3))) unsigned int*)l, 16, 0, 0);
}

// counted waits: each K-chunk "window" is exactly 4 VMEM ops per thread
// (1 A-stage DMA + 3 B b128 loads).  vmcnt is in-order [m135], so waiting
// vmcnt(4) completes everything except the newest window.
#define WAITV4() asm volatile("s_waitcnt vmcnt(4)" ::: "memory")
#define WAITV0() asm volatile("s_waitcnt vmcnt(0)" ::: "memory")

// Activations are ROW-MAJOR fp16 [R][K]: rows contiguous (384B for K=192,
// 128B-line aligned) so random neighbor gathers fetch 3 fully-used lines.

// ---------------------------------------------------------------------------
// Merged weight prep: all 10 matrices in ONE launch.
// Each: W[K,192] fp32 -> frag-ordered single fp16 plane
// (per k-chunk: [ct(12)][lane(64)][j(8)] = 6144 ushorts).
// ---------------------------------------------------------------------------
struct PrepArgs {
    const float* src[6];
    ushort*      dst[6];
    int K[6];
    int off[7];       // thread offsets (per entry: nmat*(K/32)*12*64)
};

__global__ __launch_bounds__(256) void prep_all_k(PrepArgs a)
{
    int idx = blockIdx.x * 256 + threadIdx.x;
    if (idx >= a.off[6]) return;
    int i = 0;
    #pragma unroll
    for (int t = 1; t < 6; ++t) if (idx >= a.off[t]) i = t;
    int r = idx - a.off[i];
    int K = a.K[i];
    int perMat = (K >> 5) * 12 * 64;
    int mat = r / perMat;
    r -= mat * perMat;
    int lane = r & 63;
    int ct = (r >> 6) % 12;
    int kc = r / (12 * 64);
    int col = ct * 16 + (lane & 15);
    int kb  = kc * 32 + (lane >> 4) * 8;
    const float* Wm = a.src[i] + (size_t)mat * K * HDIM;
    ushort* base = a.dst[i] + (size_t)mat * K * HDIM;
    size_t o = (size_t)kc * 6144 + (size_t)(ct * 64 + lane) * 8;
    #pragma unroll
    for (int j = 0; j < 8; ++j)
        base[o + j] = f2h(Wm[(size_t)(kb + j) * HDIM + col]);
}

// ---------------------------------------------------------------------------
// fp32 row-major [R, C] -> fp16 row-major. One thread per 8 channels.
// ---------------------------------------------------------------------------
__global__ __launch_bounds__(256) void conv_half_k(
    const float* __restrict__ src, ushort* __restrict__ dst, int R, int C)
{
    int OC = C >> 3;
    int idx = blockIdx.x * 256 + threadIdx.x;
    if (idx >= R * OC) return;
    int r = idx / OC;
    int o = idx - r * OC;
    float4 v0 = ((const float4*)(src + (size_t)r * C + o * 8))[0];
    float4 v1 = ((const float4*)(src + (size_t)r * C + o * 8))[1];
    float v[8] = {v0.x, v0.y, v0.z, v0.w, v1.x, v1.y, v1.z, v1.w};
    ushort h[8];
    #pragma unroll
    for (int t = 0; t < 8; ++t) h[t] = f2h(v[t]);
    *(uint4*)(dst + (size_t)r * C + o * 8) = pack8(h);
}

// ---------------------------------------------------------------------------
// MFMA GEMM: block 256 thr / 4 waves, tile 64 rows x 192 cols; wave tile
// 64x48.  T3+T4 counted-vmcnt pipeline (never drain vmcnt(0) in the loop):
// A chunk (64x32 fp16 = 4KB) staged into a 2x4KB LDS double buffer via
// global_load_lds dwordx4 (per-lane global src, linear LDS dest); B (3x
// b128/lane) register double-buffered.  Per chunk = exactly 4 VMEM ops, so
// the consume point waits vmcnt(4): chunk c complete, chunk c+1 IN FLIGHT
// across the raw s_barrier.  A is row-major [N][K]: lane t covers
// (row tid/4, 8 chans at (tid&3)*8) of the 64x32 chunk.
// C written fp16 row-major [N][192]; BN stats from fp32 accs.
// ---------------------------------------------------------------------------
template<bool DUAL, bool RELU, bool DEG, bool STATS>
__global__ __launch_bounds__(256, 4) void gemm_mfma_k(
    const ushort* __restrict__ A1h, const ushort* __restrict__ W1f,
    const ushort* __restrict__ A2h, const ushort* __restrict__ W2f,
    const float* __restrict__ degf, const float* __restrict__ bias,
    ushort* __restrict__ C, float* __restrict__ stats, int N, int K)
{
    __shared__ float sstat[2][HDIM];
    __shared__ __align__(16) ushort sA[2][2048];   // 2 x 4KB A-chunk dbuf
    const int tid  = threadIdx.x;
    const int wave = tid >> 6;      // 0..3 = column group (48 cols each)
    const int lane = tid & 63;
    const int row0 = blockIdx.x * 64;
    const int m16 = lane & 15;
    const int g4  = lane >> 4;

    if (STATS && tid < HDIM) { sstat[0][tid] = 0.f; sstat[1][tid] = 0.f; }

    // stage source: thread t covers 16B at (row t/4, quarter t%4) of the
    // 64x32 chunk; clamp tail rows (same semantics as old per-lane clamp)
    int srow = row0 + (tid >> 2); if (srow >= N) srow = N - 1;
    const size_t soff = (size_t)srow * K + (size_t)(tid & 3) * 8;  // ushorts
    ushort* ldst0 = &sA[0][0] + wave * 512;   // wave-uniform, +lane*16B by HW
    ushort* ldst1 = &sA[1][0] + wave * 512;

    const int nkc = K >> 5;
    const int nch = DUAL ? 2 * nkc : nkc;   // always even here (2, 6 or 12)

    auto stageA = [&](int c, int buf) {
        bool ph = DUAL && (c >= nkc);
        int kc = ph ? c - nkc : c;
        const ushort* g = (ph ? A2h : A1h) + soff + kc * 32;
        gload_lds16(g, buf ? ldst1 : ldst0);
    };
    auto loadB = [&](int c, half8* b) {
        bool ph = DUAL && (c >= nkc);
        int kc = ph ? c - nkc : c;
        const ushort* Bp = (ph ? W2f : W1f) + (size_t)kc * 6144
                         + (size_t)(wave * 192 + lane) * 8;
        #pragma unroll
        for (int ct = 0; ct < 3; ++ct)
            b[ct] = *(const half8*)(Bp + ct * 512);
    };

    floatx4 acc[4][3];
    #pragma unroll
    for (int s = 0; s < 4; ++s)
        #pragma unroll
        for (int ct = 0; ct < 3; ++ct) acc[s][ct] = (floatx4){0.f, 0.f, 0.f, 0.f};

    auto compute = [&](int buf, half8* b) {
        const ushort* aB = (buf ? &sA[1][0] : &sA[0][0]) + m16 * 32 + g4 * 8;
        half8 a[4];
        #pragma unroll
        for (int s = 0; s < 4; ++s)
            a[s] = *(const half8*)(aB + s * 512);
        #pragma unroll
        for (int ct = 0; ct < 3; ++ct)
            #pragma unroll
            for (int s = 0; s < 4; ++s)
                acc[s][ct] = __builtin_amdgcn_mfma_f32_16x16x32_f16(a[s], b[ct], acc[s][ct], 0, 0, 0);
    };

    half8 b0[3], b1[3];
    stageA(0, 0); loadB(0, b0);     // window 0: 4 VMEM ops
    stageA(1, 1); loadB(1, b1);     // window 1: 4 VMEM ops
    for (int cc = 0; cc < nch; cc += 2) {
        // ---- chunk cc (buf 0, b0); cc+1 always < nch (nch even)
        WAITV4();                               // window cc done; cc+1 in flight
        __builtin_amdgcn_s_barrier();           // A(cc) visible to all waves
        __builtin_amdgcn_sched_barrier(0);
        compute(0, b0);
        __builtin_amdgcn_s_barrier();           // all waves done reading buf0
        __builtin_amdgcn_sched_barrier(0);
        if (cc + 2 < nch) { stageA(cc + 2, 0); loadB(cc + 2, b0); }
        // ---- chunk cc+1 (buf 1, b1)
        if (cc + 2 < nch) WAITV4(); else WAITV0();
        __builtin_amdgcn_s_barrier();
        __builtin_amdgcn_sched_barrier(0);
        compute(1, b1);
        __builtin_amdgcn_s_barrier();
        __builtin_amdgcn_sched_barrier(0);
        if (cc + 3 < nch) { stageA(cc + 3, 1); loadB(cc + 3, b1); }
    }

    // epilogue: C/D layout col=lane&15, row=(lane>>4)*4+reg  [m89]
    #pragma unroll
    for (int ct = 0; ct < 3; ++ct) {
        int col = wave * 48 + ct * 16 + m16;
        float bv = bias ? bias[col] : 0.f;
        ushort* Cc = C + col;
        float lsum = 0.f, lsq = 0.f;
        #pragma unroll
        for (int s = 0; s < 4; ++s) {
            #pragma unroll
            for (int reg = 0; reg < 4; ++reg) {
                int rr = row0 + s * 16 + g4 * 4 + reg;
                if (rr < N) {
                    float v = acc[s][ct][reg] + (DEG ? degf[rr] * bv : bv);
                    if (STATS) { lsum += v; lsq += v * v; }
                    if (RELU) v = fmaxf(v, 0.f);
                    Cc[(size_t)rr * HDIM] = f2h(v);
                }
            }
        }
        if (STATS) {
            lsum += __shfl_xor(lsum, 16); lsum += __shfl_xor(lsum, 32);
            lsq  += __shfl_xor(lsq, 16);  lsq  += __shfl_xor(lsq, 32);
            if (g4 == 0) {
                atomicAdd(&sstat[0][col], lsum);
                atomicAdd(&sstat[1][col], lsq);
            }
        }
    }
    if (STATS) {
        __syncthreads();
        if (tid < HDIM) {
            atomicAdd(&stats[tid], sstat[0][tid]);
            atomicAdd(&stats[HDIM + tid], sstat[1][tid]);
        }
    }
}

// ---------------------------------------------------------------------------
// CSR construction from edge_dst
// ---------------------------------------------------------------------------
__global__ __launch_bounds__(256) void hist_k(
    const int* __restrict__ dst, int* __restrict__ deg, int E)
{
    int e = blockIdx.x * 256 + threadIdx.x;
    if (e < E) atomicAdd(&deg[dst[e]], 1);
}

__global__ __launch_bounds__(256) void block_sum_k(
    const int* __restrict__ deg, int* __restrict__ bsum, int N)
{
    __shared__ int s[256];
    int t = threadIdx.x;
    int n = blockIdx.x * 256 + t;
    s[t] = (n < N) ? deg[n] : 0;
    __syncthreads();
    for (int off = 128; off > 0; off >>= 1) {
        if (t < off) s[t] += s[t + off];
        __syncthreads();
    }
    if (t == 0) bsum[blockIdx.x] = s[0];
}

__global__ __launch_bounds__(512) void scan_bsum_k(int* __restrict__ bsum, int nb)
{
    __shared__ int s[512];
    int t = threadIdx.x;
    int v = (t < nb) ? bsum[t] : 0;
    s[t] = v;
    __syncthreads();
    for (int off = 1; off < 512; off <<= 1) {
        int u = (t >= off) ? s[t - off] : 0;
        __syncthreads();
        s[t] += u;
        __syncthreads();
    }
    if (t < nb) bsum[t] = s[t] - v;   // exclusive
}

__global__ __launch_bounds__(256) void row_ptr_k(
    const int* __restrict__ deg, const int* __restrict__ bsum,
    int* __restrict__ row_ptr, int* __restrict__ cursor,
    float* __restrict__ degf, int N, int E)
{
    __shared__ int s[256];
    int t = threadIdx.x;
    int n = blockIdx.x * 256 + t;
    int v = (n < N) ? deg[n] : 0;
    s[t] = v;
    __syncthreads();
    for (int off = 1; off < 256; off <<= 1) {
        int u = (t >= off) ? s[t - off] : 0;
        __syncthreads();
        s[t] += u;
        __syncthreads();
    }
    int ex = s[t] - v + bsum[blockIdx.x];
    if (n < N) {
        row_ptr[n] = ex;
        cursor[n]  = ex;
        degf[n]    = (float)v;
    }
    if (blockIdx.x == 0 && t == 0) row_ptr[N] = E;
}

__global__ __launch_bounds__(256) void fill_k(
    const int* __restrict__ src, const int* __restrict__ dst,
    int* __restrict__ cursor, int* __restrict__ col, int E)
{
    int e = blockIdx.x * 256 + threadIdx.x;
    if (e < E) {
        int p = atomicAdd(&cursor[dst[e]], 1);
        col[p] = src[e];
    }
}

// ---------------------------------------------------------------------------
// plain gather (layer 0, no BN): g[n] = sum_j x[col[j]]; row-major fp16.
// unroll-4: col loads hoisted so 4 neighbor-row reads are in flight.
// ---------------------------------------------------------------------------
__global__ __launch_bounds__(256) void gather_h_k(
    const ushort* __restrict__ xh, const int* __restrict__ row_ptr,
    const int* __restrict__ col, ushort* __restrict__ gh, int N, int K)
{
    int OC = K >> 3;
    int idx = blockIdx.x * 256 + threadIdx.x;
    if (idx >= N * OC) return;
    int n = idx / OC;
    int o = idx - n * OC;
    const ushort* hp = xh + o * 8;
    int j0 = row_ptr[n], j1 = row_ptr[n + 1];
    float acc[8] = {0.f,0.f,0.f,0.f,0.f,0.f,0.f,0.f};
    auto addrow = [&](uint4 hv) {
        uint hu[4] = {hv.x, hv.y, hv.z, hv.w};
        #pragma unroll
        for (int t = 0; t < 4; ++t) {
            acc[2*t]   += h2f((ushort)(hu[t] & 0xffffu));
            acc[2*t+1] += h2f((ushort)(hu[t] >> 16));
        }
    };
    int j = j0;
    for (; j + 3 < j1; j += 4) {
        int s0 = col[j], s1 = col[j+1], s2 = col[j+2], s3 = col[j+3];
        uint4 v0 = *(const uint4*)(hp + (size_t)s0 * K);
        uint4 v1 = *(const uint4*)(hp + (size_t)s1 * K);
        uint4 v2 = *(const uint4*)(hp + (size_t)s2 * K);
        uint4 v3 = *(const uint4*)(hp + (size_t)s3 * K);
        addrow(v0); addrow(v1); addrow(v2); addrow(v3);
    }
    for (; j < j1; ++j)
        addrow(*(const uint4*)(hp + (size_t)col[j] * K));
    ushort oh[8];
    #pragma unroll
    for (int t = 0; t < 8; ++t) oh[t] = f2h(acc[t]);
    *(uint4*)(gh + (size_t)n * K + o * 8) = pack8(oh);
}

// ---------------------------------------------------------------------------
// fused BN-apply + gather (layers 1..3): reads raw conv h (row-major),
// computes per-thread BN coeffs from raw sums, writes xh[n] = relu(bn(h[n]))
// and gh[n] = sum_j relu(bn(h[col j])).  unroll-4 neighbor pipeline.
// ---------------------------------------------------------------------------
__global__ __launch_bounds__(256) void gather_bn_k(
    const ushort* __restrict__ h, const float* __restrict__ stats,
    const float* __restrict__ gamma, const float* __restrict__ beta,
    float invN, const int* __restrict__ row_ptr, const int* __restrict__ col,
    ushort* __restrict__ xh, ushort* __restrict__ gh, int N)
{
    int idx = blockIdx.x * 256 + threadIdx.x;
    if (idx >= N * 24) return;
    int n = idx / 24;
    int o = idx - n * 24;
    int q = o * 8;
    float sc[8], sh[8];
    #pragma unroll
    for (int t = 0; t < 8; ++t) {
        float mu  = stats[q + t] * invN;
        float var = stats[HDIM + q + t] * invN - mu * mu;
        float s = gamma[q + t] * rsqrtf(var + EPS);
        sc[t] = s; sh[t] = beta[q + t] - mu * s;
    }
    const ushort* hp = h + q;
    // own row -> xh
    {
        uint4 hv = *(const uint4*)(hp + (size_t)n * HDIM);
        uint hu[4] = {hv.x, hv.y, hv.z, hv.w};
        ushort oh[8];
        #pragma unroll
        for (int t = 0; t < 4; ++t) {
            float v0 = h2f((ushort)(hu[t] & 0xffffu));
            float v1 = h2f((ushort)(hu[t] >> 16));
            oh[2*t]   = f2h(fmaxf(v0 * sc[2*t]   + sh[2*t],   0.f));
            oh[2*t+1] = f2h(fmaxf(v1 * sc[2*t+1] + sh[2*t+1], 0.f));
        }
        *(uint4*)(xh + (size_t)n * HDIM + q) = pack8(oh);
    }
    // neighbors -> gh
    int j0 = row_ptr[n], j1 = row_ptr[n + 1];
    float acc[8] = {0.f,0.f,0.f,0.f,0.f,0.f,0.f,0.f};
    auto addrow = [&](uint4 hv) {
        uint hu[4] = {hv.x, hv.y, hv.z, hv.w};
        #pragma unroll
        for (int t = 0; t < 4; ++t) {
            float v0 = h2f((ushort)(hu[t] & 0xffffu));
            float v1 = h2f((ushort)(hu[t] >> 16));
            acc[2*t]   += fmaxf(v0 * sc[2*t]   + sh[2*t],   0.f);
            acc[2*t+1] += fmaxf(v1 * sc[2*t+1] + sh[2*t+1], 0.f);
        }
    };
    int j = j0;
    for (; j + 3 < j1; j += 4) {
        int s0 = col[j], s1 = col[j+1], s2 = col[j+2], s3 = col[j+3];
        uint4 v0 = *(const uint4*)(hp + (size_t)s0 * HDIM);
        uint4 v1 = *(const uint4*)(hp + (size_t)s1 * HDIM);
        uint4 v2 = *(const uint4*)(hp + (size_t)s2 * HDIM);
        uint4 v3 = *(const uint4*)(hp + (size_t)s3 * HDIM);
        addrow(v0); addrow(v1); addrow(v2); addrow(v3);
    }
    for (; j < j1; ++j)
        addrow(*(const uint4*)(hp + (size_t)col[j] * HDIM));
    ushort oh[8];
    #pragma unroll
    for (int t = 0; t < 8; ++t) oh[t] = f2h(acc[t]);
    *(uint4*)(gh + (size_t)n * HDIM + q) = pack8(oh);
}

// ---------------------------------------------------------------------------
// fused final-BN + mean-pool: block per graph, thread per channel.
// Graph row range via binary search in sorted batch[]. Output fp16 row-major
// [G][192], feeding the head GEMM directly.
// ---------------------------------------------------------------------------
__global__ __launch_bounds__(192) void pool_bn_k(
    const ushort* __restrict__ h, const float* __restrict__ stats,
    const float* __restrict__ gamma, const float* __restrict__ beta,
    float invN, const int* __restrict__ batch,
    ushort* __restrict__ gsh, int G, int N)
{
    __shared__ int bounds[2];
    int g = blockIdx.x;
    int c = threadIdx.x;
    if (c < 2) {
        int key = g + c;
        int lo = 0, hi = N;
        while (lo < hi) {
            int mid = (lo + hi) >> 1;
            if (batch[mid] < key) lo = mid + 1; else hi = mid;
        }
        bounds[c] = lo;
    }
    __syncthreads();
    int r0 = bounds[0], r1 = bounds[1];
    float mu  = stats[c] * invN;
    float var = stats[HDIM + c] * invN - mu * mu;
    float sc  = gamma[c] * rsqrtf(var + EPS);
    float sh  = beta[c] - mu * sc;
    const ushort* base = h + c;
    float s = 0.f;
    for (int r = r0; r < r1; ++r)
        s += fmaxf(h2f(base[(size_t)r * HDIM]) * sc + sh, 0.f);
    float m = s / fmaxf((float)(r1 - r0), 1.f);
    gsh[(size_t)g * HDIM + c] = f2h(m);
}

// ---------------------------------------------------------------------------
// out[g] = dot(g2[g,:], Wout) + bout ; g2 is fp16 row-major
// ---------------------------------------------------------------------------
__global__ __launch_bounds__(64) void out_dot_k(
    const ushort* __restrict__ g2h, const float* __restrict__ Wout,
    const float* __restrict__ bout, float* __restrict__ out, int G)
{
    int gi = blockIdx.x;
    int t = threadIdx.x;
    float s = 0.f;
    #pragma unroll
    for (int j = 0; j < 3; ++j) {
        int c = t + j * 64;
        s += h2f(g2h[(size_t)gi * HDIM + c]) * Wout[c];
    }
    #pragma unroll
    for (int off = 32; off > 0; off >>= 1) s += __shfl_down(s, off, 64);
    if (t == 0) out[gi] = s + bout[0];
}

// ---------------------------------------------------------------------------
extern "C" void kernel_launch(void* const* d_in, const int* in_sizes, int n_in,
                              void* d_out, int out_size, void* d_ws, size_t ws_size,
                              hipStream_t stream)
{
    const float* x      = (const float*)d_in[0];
    const int*   esrc   = (const int*)d_in[1];
    const int*   edst   = (const int*)d_in[2];
    const int*   batch  = (const int*)d_in[3];
    const float* Wrel0  = (const float*)d_in[4];
    const float* brel0  = (const float*)d_in[5];
    const float* Wroot0 = (const float*)d_in[6];
    const float* Wrel   = (const float*)d_in[7];
    const float* brel   = (const float*)d_in[8];
    const float* Wroot  = (const float*)d_in[9];
    const float* gamma  = (const float*)d_in[10];
    const float* beta   = (const float*)d_in[11];
    const float* Wh1    = (const float*)d_in[12];
    const float* bh1    = (const float*)d_in[13];
    const float* Wh2    = (const float*)d_in[14];
    const float* bh2    = (const float*)d_in[15];
    const float* Wout   = (const float*)d_in[16];
    const float* bout   = (const float*)d_in[17];
    float* out = (float*)d_out;

    const int N  = in_sizes[3];           // 100000
    const int E  = in_sizes[1];           // 400000
    const int K0 = in_sizes[0] / N;       // 32
    const int G  = out_size;              // 2000
    const int nBlocks = (N + 255) / 256;
    const float invN = 1.0f / (float)N;

    char* p = (char*)d_ws;
    auto carve = [&](size_t bytes) -> void* {
        void* r = (void*)p; p += (bytes + 255) & ~(size_t)255; return r;
    };
    ushort* bufa_h= (ushort*)carve((size_t)N * HDIM * 2);   // raw conv, row-major fp16
    ushort* xh    = (ushort*)carve((size_t)N * HDIM * 2);
    ushort* gh    = (ushort*)carve((size_t)N * HDIM * 2);
    ushort* gsh   = (ushort*)carve((size_t)G * HDIM * 2);
    ushort* g1h   = (ushort*)carve((size_t)G * HDIM * 2);
    ushort* g2h   = (ushort*)carve((size_t)G * HDIM * 2);
    // deg + bnsums adjacent -> single memset
    int*    deg   = (int*)   carve((size_t)N * 4);
    float*  bnsums= (float*) carve(4 * 2 * HDIM * 4);
    size_t  zspan = (char*)(bnsums + 4 * 2 * HDIM) - (char*)deg;
    float*  degf  = (float*) carve((size_t)N * 4);
    int*    row_ptr=(int*)   carve((size_t)(N + 1) * 4);
    int*    cursor= (int*)   carve((size_t)N * 4);
    int*    col   = (int*)   carve((size_t)E * 4);
    int*    bsum  = (int*)   carve((size_t)nBlocks * 4);
    ushort* Wrel0f= (ushort*)carve((size_t)K0 * HDIM * 2);
    ushort* Wroot0f=(ushort*)carve((size_t)K0 * HDIM * 2);
    ushort* Wrelf = (ushort*)carve((size_t)3 * HDIM * HDIM * 2);
    ushort* Wrootf= (ushort*)carve((size_t)3 * HDIM * HDIM * 2);
    ushort* Wh1f  = (ushort*)carve((size_t)HDIM * HDIM * 2);
    ushort* Wh2f  = (ushort*)carve((size_t)HDIM * HDIM * 2);

    dim3 b256(256);
    const int eBlocks = (E + 255) / 256;
    const int gemmN = (N + 63) / 64;
    const int gemmG = (G + 63) / 64;

    // ---- merged weight prep (1 launch)
    {
        PrepArgs a;
        int t0 = (K0 >> 5) * 12 * 64;        // 768
        int t1 = (HDIM >> 5) * 12 * 64;      // 4608
        a.src[0] = Wrel0;  a.dst[0] = Wrel0f;  a.K[0] = K0;
        a.src[1] = Wroot0; a.dst[1] = Wroot0f; a.K[1] = K0;
        a.src[2] = Wrel;   a.dst[2] = Wrelf;   a.K[2] = HDIM;
        a.src[3] = Wroot;  a.dst[3] = Wrootf;  a.K[3] = HDIM;
        a.src[4] = Wh1;    a.dst[4] = Wh1f;    a.K[4] = HDIM;
        a.src[5] = Wh2;    a.dst[5] = Wh2f;    a.K[5] = HDIM;
        a.off[0] = 0;
        a.off[1] = a.off[0] + t0;
        a.off[2] = a.off[1] + t0;
        a.off[3] = a.off[2] + 3 * t1;
        a.off[4] = a.off[3] + 3 * t1;
        a.off[5] = a.off[4] + t1;
        a.off[6] = a.off[5] + t1;
        prep_all_k<<<(a.off[6] + 255) / 256, b256, 0, stream>>>(a);
    }
    // x -> row-major fp16 [N][32]
    conv_half_k<<<((N * (K0 >> 3)) + 255) / 256, b256, 0, stream>>>(x, xh, N, K0);

    // ---- CSR build
    hipMemsetAsync(deg, 0, zspan, stream);   // zeros deg + bnsums
    hist_k<<<eBlocks, b256, 0, stream>>>(edst, deg, E);
    block_sum_k<<<nBlocks, b256, 0, stream>>>(deg, bsum, N);
    scan_bsum_k<<<1, dim3(512), 0, stream>>>(bsum, nBlocks);
    row_ptr_k<<<nBlocks, b256, 0, stream>>>(deg, bsum, row_ptr, cursor, degf, N, E);
    fill_k<<<eBlocks, b256, 0, stream>>>(esrc, edst, cursor, col, E);

    // ---- layer 0 (input x, no BN on input)
    gather_h_k<<<((N * (K0 >> 3)) + 255) / 256, b256, 0, stream>>>(
        xh, row_ptr, col, gh, N, K0);
    gemm_mfma_k<true, false, true, true><<<gemmN, b256, 0, stream>>>(
        gh, Wrel0f, xh, Wroot0f, degf, brel0, bufa_h, bnsums, N, K0);

    // ---- layers 1..3: fused BN-apply + gather, then GEMM
    for (int l = 1; l < 4; ++l) {
        const ushort* Wrf = Wrelf  + (size_t)(l - 1) * HDIM * HDIM;
        const ushort* Wtf = Wrootf + (size_t)(l - 1) * HDIM * HDIM;
        const float*  br  = brel   + (size_t)(l - 1) * HDIM;
        gather_bn_k<<<(N * 24 + 255) / 256, b256, 0, stream>>>(
            bufa_h, bnsums + (l - 1) * 2 * HDIM,
            gamma + (l - 1) * HDIM, beta + (l - 1) * HDIM, invN,
            row_ptr, col, xh, gh, N);
        gemm_mfma_k<true, false, true, true><<<gemmN, b256, 0, stream>>>(
            gh, Wrf, xh, Wtf, degf, br, bufa_h, bnsums + l * 2 * HDIM, N, HDIM);
    }

    // ---- fused final BN + mean pool -> fp16 row-major head input
    pool_bn_k<<<G, dim3(192), 0, stream>>>(
        bufa_h, bnsums + 3 * 2 * HDIM, gamma + 3 * HDIM, beta + 3 * HDIM,
        invN, batch, gsh, G, N);

    // ---- head MLP (MFMA path, row-major fp16 end-to-end)
    gemm_mfma_k<false, true, false, false><<<gemmG, b256, 0, stream>>>(
        gsh, Wh1f, nullptr, nullptr, nullptr, bh1, g1h, nullptr, G, HDIM);
    gemm_mfma_k<false, false, false, false><<<gemmG, b256, 0, stream>>>(
        g1h, Wh2f, nullptr, nullptr, nullptr, bh2, g2h, nullptr, G, HDIM);
    out_dot_k<<<G, dim3(64), 0, stream>>>(g2h, Wout, bout, out, G);
}

// Round 4
// 531.893 us; speedup vs baseline: 1.2021x; 1.0609x over previous
//
#include <hip/hip_runtime.h>

#define HDIM 192
#define EPS 1e-5f

typedef __attribute__((ext_vector_type(8))) _Float16 half8;
typedef __attribute__((ext_vector_type(4))) float floatx4;

__device__ __forceinline__ float h2f(ushort u) {
    union { ushort u; _Float16 h; } c; c.u = u; return (float)c.h;
}
__device__ __forceinline__ ushort f2h(float x) {
    _Float16 h = (_Float16)x;           // RTN
    union { _Float16 h; ushort u; } c; c.h = h; return c.u;
}
__device__ __forceinline__ uint4 pack8(const ushort* h) {
    uint4 p;
    p.x = h[0] | ((uint)h[1] << 16); p.y = h[2] | ((uint)h[3] << 16);
    p.z = h[4] | ((uint)h[5] << 16); p.w = h[6] | ((uint)h[7] << 16);
    return p;
}

// async global->LDS DMA, 16B per lane; LDS dest = wave-uniform base + lane*16
__device__ __forceinline__ void gload_lds16(const ushort* g, ushort* l) {
    __builtin_amdgcn_global_load_lds(
        (const __attribute__((address_space(1))) unsigned int*)g,
        (__attribute__((address_space(3))) unsigned int*)l, 16, 0, 0);
}

// counted vmcnt waits with compile-time immediates (values used: 0,3,7,8)
template<int M>
__device__ __forceinline__ void waitv() {
    if constexpr (M == 0)      asm volatile("s_waitcnt vmcnt(0)" ::: "memory");
    else if constexpr (M == 3) asm volatile("s_waitcnt vmcnt(3)" ::: "memory");
    else if constexpr (M == 7) asm volatile("s_waitcnt vmcnt(7)" ::: "memory");
    else                       asm volatile("s_waitcnt vmcnt(8)" ::: "memory");
}

// Activations are ROW-MAJOR fp16 [R][K]: rows contiguous (384B for K=192,
// 128B-line aligned) so random neighbor gathers fetch 3 fully-used lines.

// ---------------------------------------------------------------------------
// Merged weight prep: all 10 matrices in ONE launch.
// Each: W[K,192] fp32 -> frag-ordered single fp16 plane
// (per k-chunk: [ct(12)][lane(64)][j(8)] = 6144 ushorts).
// ---------------------------------------------------------------------------
struct PrepArgs {
    const float* src[6];
    ushort*      dst[6];
    int K[6];
    int off[7];       // thread offsets (per entry: nmat*(K/32)*12*64)
};

__global__ __launch_bounds__(256) void prep_all_k(PrepArgs a)
{
    int idx = blockIdx.x * 256 + threadIdx.x;
    if (idx >= a.off[6]) return;
    int i = 0;
    #pragma unroll
    for (int t = 1; t < 6; ++t) if (idx >= a.off[t]) i = t;
    int r = idx - a.off[i];
    int K = a.K[i];
    int perMat = (K >> 5) * 12 * 64;
    int mat = r / perMat;
    r -= mat * perMat;
    int lane = r & 63;
    int ct = (r >> 6) % 12;
    int kc = r / (12 * 64);
    int col = ct * 16 + (lane & 15);
    int kb  = kc * 32 + (lane >> 4) * 8;
    const float* Wm = a.src[i] + (size_t)mat * K * HDIM;
    ushort* base = a.dst[i] + (size_t)mat * K * HDIM;
    size_t o = (size_t)kc * 6144 + (size_t)(ct * 64 + lane) * 8;
    #pragma unroll
    for (int j = 0; j < 8; ++j)
        base[o + j] = f2h(Wm[(size_t)(kb + j) * HDIM + col]);
}

// ---------------------------------------------------------------------------
// fp32 row-major [R, C] -> fp16 row-major. One thread per 8 channels.
// ---------------------------------------------------------------------------
__global__ __launch_bounds__(256) void conv_half_k(
    const float* __restrict__ src, ushort* __restrict__ dst, int R, int C)
{
    int OC = C >> 3;
    int idx = blockIdx.x * 256 + threadIdx.x;
    if (idx >= R * OC) return;
    int r = idx / OC;
    int o = idx - r * OC;
    float4 v0 = ((const float4*)(src + (size_t)r * C + o * 8))[0];
    float4 v1 = ((const float4*)(src + (size_t)r * C + o * 8))[1];
    float v[8] = {v0.x, v0.y, v0.z, v0.w, v1.x, v1.y, v1.z, v1.w};
    ushort h[8];
    #pragma unroll
    for (int t = 0; t < 8; ++t) h[t] = f2h(v[t]);
    *(uint4*)(dst + (size_t)r * C + o * 8) = pack8(h);
}

// ---------------------------------------------------------------------------
// MFMA GEMM: block 256 thr / 4 waves, tile 64 rows x 192 cols; wave tile
// 64x48.  Rolling prefetch: A chunks (64x32 fp16 = 4KB) staged depth-3
// ahead into a 5-slot LDS ring via global_load_lds dwordx4; B (3x b128/lane)
// register-rotated depth-2.  Per chunk issue = {A_{c+3}, B_{c+2}}; consume
// waits vmcnt(8) (tail 7/3/0) -- chunk c complete, 3 A-chunks + 2 B-sets
// stay IN FLIGHT across the single per-chunk s_barrier.  5-slot ring makes
// the buffer-reuse barrier unnecessary (writer-reader distance >= 3 under
// max 1-barrier wave skew).  NCH (#chunks) is a template param so the loop
// fully unrolls with static slot indices and exact tail waits.
// Epilogue: acc -> LDS C-tile [64][200] fp16 (pad kills bank alias) -> one
// linear 24KB burst per block (no 2B-scatter RMW at HBM).
// BN stats from fp32 accs.
// ---------------------------------------------------------------------------
template<bool DUAL, bool RELU, bool DEG, bool STATS, int NCH>
__global__ __launch_bounds__(256, 4) void gemm_mfma_k(
    const ushort* __restrict__ A1h, const ushort* __restrict__ W1f,
    const ushort* __restrict__ A2h, const ushort* __restrict__ W2f,
    const float* __restrict__ degf, const float* __restrict__ bias,
    ushort* __restrict__ C, float* __restrict__ stats, int N, int K)
{
    __shared__ float sstat[2][HDIM];
    // 25.6KB shared: K-loop = 5 x 4KB A-stage ring; epilogue = [64][200] C-tile
    __shared__ __align__(16) ushort smem[12800];
    const int tid  = threadIdx.x;
    const int wave = tid >> 6;      // 0..3 = column group (48 cols each)
    const int lane = tid & 63;
    const int row0 = blockIdx.x * 64;
    const int m16 = lane & 15;
    const int g4  = lane >> 4;

    if (STATS && tid < HDIM) { sstat[0][tid] = 0.f; sstat[1][tid] = 0.f; }

    // stage source: thread t covers 16B at (row t/4, quarter t%4) of the
    // 64x32 chunk; clamp tail rows (output rows >= N are discarded)
    int srow = row0 + (tid >> 2); if (srow >= N) srow = N - 1;
    const size_t soff = (size_t)srow * K + (size_t)(tid & 3) * 8;  // ushorts

    const int nkc = K >> 5;         // chunks per phase (DUAL: NCH = 2*nkc)

    auto stageA = [&](int c, int slot) {
        bool ph = DUAL && (c >= nkc);
        int kc = ph ? c - nkc : c;
        const ushort* g = (ph ? A2h : A1h) + soff + kc * 32;
        gload_lds16(g, smem + slot * 2048 + wave * 512);
    };
    auto loadB = [&](int c, half8* b) {
        bool ph = DUAL && (c >= nkc);
        int kc = ph ? c - nkc : c;
        const ushort* Bp = (ph ? W2f : W1f) + (size_t)kc * 6144
                         + (size_t)(wave * 192 + lane) * 8;
        #pragma unroll
        for (int ct = 0; ct < 3; ++ct)
            b[ct] = *(const half8*)(Bp + ct * 512);
    };

    floatx4 acc[4][3];
    #pragma unroll
    for (int s = 0; s < 4; ++s)
        #pragma unroll
        for (int ct = 0; ct < 3; ++ct) acc[s][ct] = (floatx4){0.f, 0.f, 0.f, 0.f};

    auto compute = [&](int slot, const half8* b) {
        const ushort* aB = smem + slot * 2048 + m16 * 32 + g4 * 8;
        half8 a[4];
        #pragma unroll
        for (int s = 0; s < 4; ++s)
            a[s] = *(const half8*)(aB + s * 512);
        #pragma unroll
        for (int ct = 0; ct < 3; ++ct)
            #pragma unroll
            for (int s = 0; s < 4; ++s)
                acc[s][ct] = __builtin_amdgcn_mfma_f32_16x16x32_f16(a[s], b[ct], acc[s][ct], 0, 0, 0);
    };

    half8 breg[3][3];
    // prologue: A0..A2 (depth 3), B0..B1 (depth 2)
    stageA(0, 0); stageA(1, 1);
    if constexpr (NCH >= 3) stageA(2, 2);
    loadB(0, breg[0]); loadB(1, breg[1]);

    #pragma unroll
    for (int c = 0; c < NCH; ++c) {
        if (c + 3 < NCH) stageA(c + 3, (c + 3) % 5);
        if (c + 2 < NCH) loadB(c + 2, breg[(c + 2) % 3]);
        const int rem = NCH - 1 - c;
        if      (rem >= 3) waitv<8>();
        else if (rem == 2) waitv<7>();
        else if (rem == 1) waitv<3>();
        else               waitv<0>();
        __builtin_amdgcn_s_barrier();           // A(c) staged by all 4 waves
        __builtin_amdgcn_sched_barrier(0);
        compute(c % 5, breg[c % 3]);
    }

    // ---- epilogue: acc -> LDS C-tile -> linear global burst
    __syncthreads();                // all waves done with the staging ring
    // C/D layout col=lane&15, row=(lane>>4)*4+reg  [m89]
    #pragma unroll
    for (int ct = 0; ct < 3; ++ct) {
        int col = wave * 48 + ct * 16 + m16;
        float bv = bias ? bias[col] : 0.f;
        float lsum = 0.f, lsq = 0.f;
        #pragma unroll
        for (int s = 0; s < 4; ++s) {
            #pragma unroll
            for (int reg = 0; reg < 4; ++reg) {
                int rloc = s * 16 + g4 * 4 + reg;
                int rr = row0 + rloc;
                int rrc = rr < N ? rr : N - 1;
                float v = acc[s][ct][reg] + (DEG ? degf[rrc] * bv : bv);
                if (STATS && rr < N) { lsum += v; lsq += v * v; }
                if (RELU) v = fmaxf(v, 0.f);
                smem[rloc * 200 + col] = f2h(v);
            }
        }
        if (STATS) {
            lsum += __shfl_xor(lsum, 16); lsum += __shfl_xor(lsum, 32);
            lsq  += __shfl_xor(lsq, 16);  lsq  += __shfl_xor(lsq, 32);
            if (g4 == 0) {
                atomicAdd(&sstat[0][col], lsum);
                atomicAdd(&sstat[1][col], lsq);
            }
        }
    }
    __syncthreads();                // C-tile complete
    {
        int rowsLeft = N - row0; if (rowsLeft > 64) rowsLeft = 64;
        int lim = rowsLeft * 24;    // uint4 count (24 per row)
        ushort* Cb = C + (size_t)row0 * HDIM;
        #pragma unroll
        for (int k = 0; k < 6; ++k) {
            int u = tid + k * 256;
            if (u < lim) {
                int r  = u / 24;
                int c8 = (u - r * 24) * 8;
                *(uint4*)(Cb + (size_t)u * 8) =
                    *(const uint4*)(smem + r * 200 + c8);
            }
        }
    }
    if (STATS) {
        if (tid < HDIM) {
            atomicAdd(&stats[tid], sstat[0][tid]);
            atomicAdd(&stats[HDIM + tid], sstat[1][tid]);
        }
    }
}

// ---------------------------------------------------------------------------
// CSR construction from edge_dst
// ---------------------------------------------------------------------------
__global__ __launch_bounds__(256) void hist_k(
    const int* __restrict__ dst, int* __restrict__ deg, int E)
{
    int e = blockIdx.x * 256 + threadIdx.x;
    if (e < E) atomicAdd(&deg[dst[e]], 1);
}

__global__ __launch_bounds__(256) void block_sum_k(
    const int* __restrict__ deg, int* __restrict__ bsum, int N)
{
    __shared__ int s[256];
    int t = threadIdx.x;
    int n = blockIdx.x * 256 + t;
    s[t] = (n < N) ? deg[n] : 0;
    __syncthreads();
    for (int off = 128; off > 0; off >>= 1) {
        if (t < off) s[t] += s[t + off];
        __syncthreads();
    }
    if (t == 0) bsum[blockIdx.x] = s[0];
}

__global__ __launch_bounds__(512) void scan_bsum_k(int* __restrict__ bsum, int nb)
{
    __shared__ int s[512];
    int t = threadIdx.x;
    int v = (t < nb) ? bsum[t] : 0;
    s[t] = v;
    __syncthreads();
    for (int off = 1; off < 512; off <<= 1) {
        int u = (t >= off) ? s[t - off] : 0;
        __syncthreads();
        s[t] += u;
        __syncthreads();
    }
    if (t < nb) bsum[t] = s[t] - v;   // exclusive
}

__global__ __launch_bounds__(256) void row_ptr_k(
    const int* __restrict__ deg, const int* __restrict__ bsum,
    int* __restrict__ row_ptr, int* __restrict__ cursor,
    float* __restrict__ degf, int N, int E)
{
    __shared__ int s[256];
    int t = threadIdx.x;
    int n = blockIdx.x * 256 + t;
    int v = (n < N) ? deg[n] : 0;
    s[t] = v;
    __syncthreads();
    for (int off = 1; off < 256; off <<= 1) {
        int u = (t >= off) ? s[t - off] : 0;
        __syncthreads();
        s[t] += u;
        __syncthreads();
    }
    int ex = s[t] - v + bsum[blockIdx.x];
    if (n < N) {
        row_ptr[n] = ex;
        cursor[n]  = ex;
        degf[n]    = (float)v;
    }
    if (blockIdx.x == 0 && t == 0) row_ptr[N] = E;
}

__global__ __launch_bounds__(256) void fill_k(
    const int* __restrict__ src, const int* __restrict__ dst,
    int* __restrict__ cursor, int* __restrict__ col, int E)
{
    int e = blockIdx.x * 256 + threadIdx.x;
    if (e < E) {
        int p = atomicAdd(&cursor[dst[e]], 1);
        col[p] = src[e];
    }
}

// ---------------------------------------------------------------------------
// plain gather (layer 0, no BN): g[n] = sum_j x[col[j]]; row-major fp16.
// unroll-4: col loads hoisted so 4 neighbor-row reads are in flight.
// ---------------------------------------------------------------------------
__global__ __launch_bounds__(256) void gather_h_k(
    const ushort* __restrict__ xh, const int* __restrict__ row_ptr,
    const int* __restrict__ col, ushort* __restrict__ gh, int N, int K)
{
    int OC = K >> 3;
    int idx = blockIdx.x * 256 + threadIdx.x;
    if (idx >= N * OC) return;
    int n = idx / OC;
    int o = idx - n * OC;
    const ushort* hp = xh + o * 8;
    int j0 = row_ptr[n], j1 = row_ptr[n + 1];
    float acc[8] = {0.f,0.f,0.f,0.f,0.f,0.f,0.f,0.f};
    auto addrow = [&](uint4 hv) {
        uint hu[4] = {hv.x, hv.y, hv.z, hv.w};
        #pragma unroll
        for (int t = 0; t < 4; ++t) {
            acc[2*t]   += h2f((ushort)(hu[t] & 0xffffu));
            acc[2*t+1] += h2f((ushort)(hu[t] >> 16));
        }
    };
    int j = j0;
    for (; j + 3 < j1; j += 4) {
        int s0 = col[j], s1 = col[j+1], s2 = col[j+2], s3 = col[j+3];
        uint4 v0 = *(const uint4*)(hp + (size_t)s0 * K);
        uint4 v1 = *(const uint4*)(hp + (size_t)s1 * K);
        uint4 v2 = *(const uint4*)(hp + (size_t)s2 * K);
        uint4 v3 = *(const uint4*)(hp + (size_t)s3 * K);
        addrow(v0); addrow(v1); addrow(v2); addrow(v3);
    }
    for (; j < j1; ++j)
        addrow(*(const uint4*)(hp + (size_t)col[j] * K));
    ushort oh[8];
    #pragma unroll
    for (int t = 0; t < 8; ++t) oh[t] = f2h(acc[t]);
    *(uint4*)(gh + (size_t)n * K + o * 8) = pack8(oh);
}

// ---------------------------------------------------------------------------
// fused BN-apply + gather (layers 1..3): reads raw conv h (row-major),
// computes per-thread BN coeffs from raw sums, writes xh[n] = relu(bn(h[n]))
// and gh[n] = sum_j relu(bn(h[col j])).  unroll-4 neighbor pipeline.
// ---------------------------------------------------------------------------
__global__ __launch_bounds__(256) void gather_bn_k(
    const ushort* __restrict__ h, const float* __restrict__ stats,
    const float* __restrict__ gamma, const float* __restrict__ beta,
    float invN, const int* __restrict__ row_ptr, const int* __restrict__ col,
    ushort* __restrict__ xh, ushort* __restrict__ gh, int N)
{
    int idx = blockIdx.x * 256 + threadIdx.x;
    if (idx >= N * 24) return;
    int n = idx / 24;
    int o = idx - n * 24;
    int q = o * 8;
    float sc[8], sh[8];
    #pragma unroll
    for (int t = 0; t < 8; ++t) {
        float mu  = stats[q + t] * invN;
        float var = stats[HDIM + q + t] * invN - mu * mu;
        float s = gamma[q + t] * rsqrtf(var + EPS);
        sc[t] = s; sh[t] = beta[q + t] - mu * s;
    }
    const ushort* hp = h + q;
    // own row -> xh
    {
        uint4 hv = *(const uint4*)(hp + (size_t)n * HDIM);
        uint hu[4] = {hv.x, hv.y, hv.z, hv.w};
        ushort oh[8];
        #pragma unroll
        for (int t = 0; t < 4; ++t) {
            float v0 = h2f((ushort)(hu[t] & 0xffffu));
            float v1 = h2f((ushort)(hu[t] >> 16));
            oh[2*t]   = f2h(fmaxf(v0 * sc[2*t]   + sh[2*t],   0.f));
            oh[2*t+1] = f2h(fmaxf(v1 * sc[2*t+1] + sh[2*t+1], 0.f));
        }
        *(uint4*)(xh + (size_t)n * HDIM + q) = pack8(oh);
    }
    // neighbors -> gh
    int j0 = row_ptr[n], j1 = row_ptr[n + 1];
    float acc[8] = {0.f,0.f,0.f,0.f,0.f,0.f,0.f,0.f};
    auto addrow = [&](uint4 hv) {
        uint hu[4] = {hv.x, hv.y, hv.z, hv.w};
        #pragma unroll
        for (int t = 0; t < 4; ++t) {
            float v0 = h2f((ushort)(hu[t] & 0xffffu));
            float v1 = h2f((ushort)(hu[t] >> 16));
            acc[2*t]   += fmaxf(v0 * sc[2*t]   + sh[2*t],   0.f);
            acc[2*t+1] += fmaxf(v1 * sc[2*t+1] + sh[2*t+1], 0.f);
        }
    };
    int j = j0;
    for (; j + 3 < j1; j += 4) {
        int s0 = col[j], s1 = col[j+1], s2 = col[j+2], s3 = col[j+3];
        uint4 v0 = *(const uint4*)(hp + (size_t)s0 * HDIM);
        uint4 v1 = *(const uint4*)(hp + (size_t)s1 * HDIM);
        uint4 v2 = *(const uint4*)(hp + (size_t)s2 * HDIM);
        uint4 v3 = *(const uint4*)(hp + (size_t)s3 * HDIM);
        addrow(v0); addrow(v1); addrow(v2); addrow(v3);
    }
    for (; j < j1; ++j)
        addrow(*(const uint4*)(hp + (size_t)col[j] * HDIM));
    ushort oh[8];
    #pragma unroll
    for (int t = 0; t < 8; ++t) oh[t] = f2h(acc[t]);
    *(uint4*)(gh + (size_t)n * HDIM + q) = pack8(oh);
}

// ---------------------------------------------------------------------------
// fused final-BN + mean-pool: block per graph, thread per channel.
// Graph row range via binary search in sorted batch[]. Output fp16 row-major
// [G][192], feeding the head GEMM directly.
// ---------------------------------------------------------------------------
__global__ __launch_bounds__(192) void pool_bn_k(
    const ushort* __restrict__ h, const float* __restrict__ stats,
    const float* __restrict__ gamma, const float* __restrict__ beta,
    float invN, const int* __restrict__ batch,
    ushort* __restrict__ gsh, int G, int N)
{
    __shared__ int bounds[2];
    int g = blockIdx.x;
    int c = threadIdx.x;
    if (c < 2) {
        int key = g + c;
        int lo = 0, hi = N;
        while (lo < hi) {
            int mid = (lo + hi) >> 1;
            if (batch[mid] < key) lo = mid + 1; else hi = mid;
        }
        bounds[c] = lo;
    }
    __syncthreads();
    int r0 = bounds[0], r1 = bounds[1];
    float mu  = stats[c] * invN;
    float var = stats[HDIM + c] * invN - mu * mu;
    float sc  = gamma[c] * rsqrtf(var + EPS);
    float sh  = beta[c] - mu * sc;
    const ushort* base = h + c;
    float s = 0.f;
    for (int r = r0; r < r1; ++r)
        s += fmaxf(h2f(base[(size_t)r * HDIM]) * sc + sh, 0.f);
    float m = s / fmaxf((float)(r1 - r0), 1.f);
    gsh[(size_t)g * HDIM + c] = f2h(m);
}

// ---------------------------------------------------------------------------
// out[g] = dot(g2[g,:], Wout) + bout ; g2 is fp16 row-major
// ---------------------------------------------------------------------------
__global__ __launch_bounds__(64) void out_dot_k(
    const ushort* __restrict__ g2h, const float* __restrict__ Wout,
    const float* __restrict__ bout, float* __restrict__ out, int G)
{
    int gi = blockIdx.x;
    int t = threadIdx.x;
    float s = 0.f;
    #pragma unroll
    for (int j = 0; j < 3; ++j) {
        int c = t + j * 64;
        s += h2f(g2h[(size_t)gi * HDIM + c]) * Wout[c];
    }
    #pragma unroll
    for (int off = 32; off > 0; off >>= 1) s += __shfl_down(s, off, 64);
    if (t == 0) out[gi] = s + bout[0];
}

// ---------------------------------------------------------------------------
extern "C" void kernel_launch(void* const* d_in, const int* in_sizes, int n_in,
                              void* d_out, int out_size, void* d_ws, size_t ws_size,
                              hipStream_t stream)
{
    const float* x      = (const float*)d_in[0];
    const int*   esrc   = (const int*)d_in[1];
    const int*   edst   = (const int*)d_in[2];
    const int*   batch  = (const int*)d_in[3];
    const float* Wrel0  = (const float*)d_in[4];
    const float* brel0  = (const float*)d_in[5];
    const float* Wroot0 = (const float*)d_in[6];
    const float* Wrel   = (const float*)d_in[7];
    const float* brel   = (const float*)d_in[8];
    const float* Wroot  = (const float*)d_in[9];
    const float* gamma  = (const float*)d_in[10];
    const float* beta   = (const float*)d_in[11];
    const float* Wh1    = (const float*)d_in[12];
    const float* bh1    = (const float*)d_in[13];
    const float* Wh2    = (const float*)d_in[14];
    const float* bh2    = (const float*)d_in[15];
    const float* Wout   = (const float*)d_in[16];
    const float* bout   = (const float*)d_in[17];
    float* out = (float*)d_out;

    const int N  = in_sizes[3];           // 100000
    const int E  = in_sizes[1];           // 400000
    const int K0 = in_sizes[0] / N;       // 32
    const int G  = out_size;              // 2000
    const int nBlocks = (N + 255) / 256;
    const float invN = 1.0f / (float)N;

    char* p = (char*)d_ws;
    auto carve = [&](size_t bytes) -> void* {
        void* r = (void*)p; p += (bytes + 255) & ~(size_t)255; return r;
    };
    ushort* bufa_h= (ushort*)carve((size_t)N * HDIM * 2);   // raw conv, row-major fp16
    ushort* xh    = (ushort*)carve((size_t)N * HDIM * 2);
    ushort* gh    = (ushort*)carve((size_t)N * HDIM * 2);
    ushort* gsh   = (ushort*)carve((size_t)G * HDIM * 2);
    ushort* g1h   = (ushort*)carve((size_t)G * HDIM * 2);
    ushort* g2h   = (ushort*)carve((size_t)G * HDIM * 2);
    // deg + bnsums adjacent -> single memset
    int*    deg   = (int*)   carve((size_t)N * 4);
    float*  bnsums= (float*) carve(4 * 2 * HDIM * 4);
    size_t  zspan = (char*)(bnsums + 4 * 2 * HDIM) - (char*)deg;
    float*  degf  = (float*) carve((size_t)N * 4);
    int*    row_ptr=(int*)   carve((size_t)(N + 1) * 4);
    int*    cursor= (int*)   carve((size_t)N * 4);
    int*    col   = (int*)   carve((size_t)E * 4);
    int*    bsum  = (int*)   carve((size_t)nBlocks * 4);
    ushort* Wrel0f= (ushort*)carve((size_t)K0 * HDIM * 2);
    ushort* Wroot0f=(ushort*)carve((size_t)K0 * HDIM * 2);
    ushort* Wrelf = (ushort*)carve((size_t)3 * HDIM * HDIM * 2);
    ushort* Wrootf= (ushort*)carve((size_t)3 * HDIM * HDIM * 2);
    ushort* Wh1f  = (ushort*)carve((size_t)HDIM * HDIM * 2);
    ushort* Wh2f  = (ushort*)carve((size_t)HDIM * HDIM * 2);

    dim3 b256(256);
    const int eBlocks = (E + 255) / 256;
    const int gemmN = (N + 63) / 64;
    const int gemmG = (G + 63) / 64;

    // ---- merged weight prep (1 launch)
    {
        PrepArgs a;
        int t0 = (K0 >> 5) * 12 * 64;        // 768
        int t1 = (HDIM >> 5) * 12 * 64;      // 4608
        a.src[0] = Wrel0;  a.dst[0] = Wrel0f;  a.K[0] = K0;
        a.src[1] = Wroot0; a.dst[1] = Wroot0f; a.K[1] = K0;
        a.src[2] = Wrel;   a.dst[2] = Wrelf;   a.K[2] = HDIM;
        a.src[3] = Wroot;  a.dst[3] = Wrootf;  a.K[3] = HDIM;
        a.src[4] = Wh1;    a.dst[4] = Wh1f;    a.K[4] = HDIM;
        a.src[5] = Wh2;    a.dst[5] = Wh2f;    a.K[5] = HDIM;
        a.off[0] = 0;
        a.off[1] = a.off[0] + t0;
        a.off[2] = a.off[1] + t0;
        a.off[3] = a.off[2] + 3 * t1;
        a.off[4] = a.off[3] + 3 * t1;
        a.off[5] = a.off[4] + t1;
        a.off[6] = a.off[5] + t1;
        prep_all_k<<<(a.off[6] + 255) / 256, b256, 0, stream>>>(a);
    }
    // x -> row-major fp16 [N][32]
    conv_half_k<<<((N * (K0 >> 3)) + 255) / 256, b256, 0, stream>>>(x, xh, N, K0);

    // ---- CSR build
    hipMemsetAsync(deg, 0, zspan, stream);   // zeros deg + bnsums
    hist_k<<<eBlocks, b256, 0, stream>>>(edst, deg, E);
    block_sum_k<<<nBlocks, b256, 0, stream>>>(deg, bsum, N);
    scan_bsum_k<<<1, dim3(512), 0, stream>>>(bsum, nBlocks);
    row_ptr_k<<<nBlocks, b256, 0, stream>>>(deg, bsum, row_ptr, cursor, degf, N, E);
    fill_k<<<eBlocks, b256, 0, stream>>>(esrc, edst, cursor, col, E);

    // ---- layer 0 (input x, no BN on input): K=32 dual -> NCH=2
    gather_h_k<<<((N * (K0 >> 3)) + 255) / 256, b256, 0, stream>>>(
        xh, row_ptr, col, gh, N, K0);
    gemm_mfma_k<true, false, true, true, 2><<<gemmN, b256, 0, stream>>>(
        gh, Wrel0f, xh, Wroot0f, degf, brel0, bufa_h, bnsums, N, K0);

    // ---- layers 1..3: fused BN-apply + gather, then GEMM (K=192 dual -> NCH=12)
    for (int l = 1; l < 4; ++l) {
        const ushort* Wrf = Wrelf  + (size_t)(l - 1) * HDIM * HDIM;
        const ushort* Wtf = Wrootf + (size_t)(l - 1) * HDIM * HDIM;
        const float*  br  = brel   + (size_t)(l - 1) * HDIM;
        gather_bn_k<<<(N * 24 + 255) / 256, b256, 0, stream>>>(
            bufa_h, bnsums + (l - 1) * 2 * HDIM,
            gamma + (l - 1) * HDIM, beta + (l - 1) * HDIM, invN,
            row_ptr, col, xh, gh, N);
        gemm_mfma_k<true, false, true, true, 12><<<gemmN, b256, 0, stream>>>(
            gh, Wrf, xh, Wtf, degf, br, bufa_h, bnsums + l * 2 * HDIM, N, HDIM);
    }

    // ---- fused final BN + mean pool -> fp16 row-major head input
    pool_bn_k<<<G, dim3(192), 0, stream>>>(
        bufa_h, bnsums + 3 * 2 * HDIM, gamma + 3 * HDIM, beta + 3 * HDIM,
        invN, batch, gsh, G, N);

    // ---- head MLP (MFMA path, row-major fp16 end-to-end; K=192 -> NCH=6)
    gemm_mfma_k<false, true, false, false, 6><<<gemmG, b256, 0, stream>>>(
        gsh, Wh1f, nullptr, nullptr, nullptr, bh1, g1h, nullptr, G, HDIM);
    gemm_mfma_k<false, false, false, false, 6><<<gemmG, b256, 0, stream>>>(
        g1h, Wh2f, nullptr, nullptr, nullptr, bh2, g2h, nullptr, G, HDIM);
    out_dot_k<<<G, dim3(64), 0, stream>>>(g2h, Wout, bout, out, G);
}